// Round 1
// baseline (618.653 us; speedup 1.0000x reference)
//
#include <hip/hip_runtime.h>
#include <hip/hip_bf16.h>

#define T_SEQ 8192
#define NE 1024
#define FF 4096

typedef __bf16 bf16_t;
typedef __bf16 bf16x8 __attribute__((ext_vector_type(8)));
typedef __bf16 bf16x4 __attribute__((ext_vector_type(4)));
typedef float f32x4 __attribute__((ext_vector_type(4)));

__device__ __forceinline__ void gll16(const void* g, void* l) {
    __builtin_amdgcn_global_load_lds(
        (const __attribute__((address_space(1))) void*)g,
        (__attribute__((address_space(3))) void*)l, 16, 0, 0);
}

// ---------------- elementwise cast fp32 -> bf16 (x4 per thread) ----------------
__global__ __launch_bounds__(256) void cast_f32_bf16(const float* __restrict__ in,
                                                     bf16_t* __restrict__ out, int n4) {
    int i = blockIdx.x * 256 + threadIdx.x;
    if (i >= n4) return;
    float4 v = ((const float4*)in)[i];
    bf16x4 h;
    h[0] = (bf16_t)v.x; h[1] = (bf16_t)v.y; h[2] = (bf16_t)v.z; h[3] = (bf16_t)v.w;
    ((bf16x4*)out)[i] = h;
}

// ---------------- build packed [Wk | Wq*0.125 | Wv | 0pad] as (256 x 1024) bf16, N-major ----------------
__global__ __launch_bounds__(256) void build_wkqv(const float* __restrict__ Wk,
                                                  const float* __restrict__ Wq,
                                                  const float* __restrict__ Wv,
                                                  bf16_t* __restrict__ out) {
    int idx = blockIdx.x * 256 + threadIdx.x;   // over 256*1024
    int n  = idx >> 10;   // 0..255  (output head-col)
    int kk = idx & 1023;  // 0..1023 (embd)
    float v = 0.f;
    if (n < 64)       v = Wk[kk * 64 + n];
    else if (n < 128) v = Wq[kk * 64 + (n - 64)] * 0.125f;  // fold 1/sqrt(hs)
    else if (n < 192) v = Wv[kk * 64 + (n - 128)];
    out[idx] = (bf16_t)v;
}

// ---------------- tiled transpose + cast: in (R x C) f32 -> out (C x R) bf16 ----------------
__global__ __launch_bounds__(256) void tcast(const float* __restrict__ in,
                                             bf16_t* __restrict__ out, int R, int C) {
    __shared__ bf16_t tl[64][66];
    const int bc = blockIdx.x << 6, br = blockIdx.y << 6;
    const int tx = threadIdx.x & 63, ty = threadIdx.x >> 6;
#pragma unroll
    for (int j = 0; j < 16; ++j) {
        const int r = ty + j * 4;
        tl[r][tx] = (bf16_t)in[(size_t)(br + r) * C + bc + tx];
    }
    __syncthreads();
#pragma unroll
    for (int j = 0; j < 16; ++j) {
        const int r = ty + j * 4;
        out[(size_t)(bc + r) * R + br + tx] = tl[tx][r];
    }
}

// ---------------- main GEMM: C(MxN) = A(MxK,bf16) @ Bt(NxK,bf16)^T, templated epilogue ----
// EPI 0: split k/q/vT stores (N=256 padded, cols 0-63 k, 64-127 q, 128-191 v^T)
// EPI 1: outf = res + C                (proj + residual)
// EPI 2: ob0  = bf16(relu(C + bias))   (FFN1)
// EPI 3: outf = res + C + bias         (FFN2 + residual)
template <int EPI>
__global__ __launch_bounds__(256, 2)
void gemm_bt(const bf16_t* __restrict__ A, const bf16_t* __restrict__ Bt,
             int M, int N, int K,
             float* __restrict__ outf,
             bf16_t* __restrict__ ob0, bf16_t* __restrict__ ob1, bf16_t* __restrict__ ob2,
             const float* __restrict__ res, const float* __restrict__ bias) {
    const int tid  = threadIdx.x;
    const int lane = tid & 63;
    const int tiles_n = N >> 7;
    const int tm = blockIdx.x / tiles_n;
    const int tn = blockIdx.x % tiles_n;
    const int brow = tm << 7, bcol = tn << 7;

    __shared__ __align__(16) bf16_t As[128 * 32];
    __shared__ __align__(16) bf16_t Bs[128 * 32];

    // staging: 512 chunks of 16B per tile; chunk c = row(c>>2), kblk(c&3).
    // XOR-swizzle the SOURCE k-chunk by g(row)=(row>>1)&3 so ds_read_b128 is ~2-way.
    const int c1 = tid, c2 = tid + 256;
    const int s1 = (((c1 & 3) ^ ((c1 >> 3) & 3)) * 8);
    const int s2 = (((c2 & 3) ^ ((c2 >> 3) & 3)) * 8);
    const bf16_t* gA1 = A + (size_t)(brow + (c1 >> 2)) * K + s1;
    const bf16_t* gA2 = A + (size_t)(brow + (c2 >> 2)) * K + s2;
    const bf16_t* gB1 = Bt + (size_t)(bcol + (c1 >> 2)) * K + s1;
    const bf16_t* gB2 = Bt + (size_t)(bcol + (c2 >> 2)) * K + s2;
    bf16_t* lA1 = As + c1 * 8; bf16_t* lA2 = As + c2 * 8;
    bf16_t* lB1 = Bs + c1 * 8; bf16_t* lB2 = Bs + c2 * 8;

    const int wv = tid >> 6;
    const int wr = (wv >> 1) * 64, wc = (wv & 1) * 64;
    const int arow  = wr + (lane & 15);
    const int brf   = wc + (lane & 15);
    // read-side swizzled k-offset: kblk = lane>>4, g = (lane>>1)&3 (bits 1-2 of in-tile row)
    const int koff = (((lane >> 4) ^ ((lane >> 1) & 3)) * 8);

    f32x4 acc[4][4];
#pragma unroll
    for (int i = 0; i < 4; ++i)
#pragma unroll
        for (int j = 0; j < 4; ++j) acc[i][j] = (f32x4){0.f, 0.f, 0.f, 0.f};

    for (int k0 = 0; k0 < K; k0 += 32) {
        gll16(gA1, lA1); gll16(gA2, lA2);
        gll16(gB1, lB1); gll16(gB2, lB2);
        gA1 += 32; gA2 += 32; gB1 += 32; gB2 += 32;
        __syncthreads();
        bf16x8 af[4], bfr[4];
#pragma unroll
        for (int mi = 0; mi < 4; ++mi)
            af[mi] = *(const bf16x8*)(As + (arow + mi * 16) * 32 + koff);
#pragma unroll
        for (int ni = 0; ni < 4; ++ni)
            bfr[ni] = *(const bf16x8*)(Bs + (brf + ni * 16) * 32 + koff);
#pragma unroll
        for (int mi = 0; mi < 4; ++mi)
#pragma unroll
            for (int ni = 0; ni < 4; ++ni)
                acc[mi][ni] = __builtin_amdgcn_mfma_f32_16x16x32_bf16(
                    af[mi], bfr[ni], acc[mi][ni], 0, 0, 0);
        __syncthreads();
    }

    // C/D layout: col = lane&15, row = (lane>>4)*4 + reg
    const int r0 = brow + wr + ((lane >> 4) << 2);
    const int c0 = bcol + wc + (lane & 15);
#pragma unroll
    for (int mi = 0; mi < 4; ++mi)
#pragma unroll
        for (int ni = 0; ni < 4; ++ni)
#pragma unroll
            for (int r = 0; r < 4; ++r) {
                const int row = r0 + mi * 16 + r;
                const int col = c0 + ni * 16;
                const float v = acc[mi][ni][r];
                if constexpr (EPI == 0) {
                    if (col < 64)       ob0[row * 64 + col] = (bf16_t)v;             // k
                    else if (col < 128) ob1[row * 64 + (col - 64)] = (bf16_t)v;      // q (pre-scaled)
                    else if (col < 192) ob2[(size_t)(col - 128) * T_SEQ + row] = (bf16_t)v; // v^T
                } else if constexpr (EPI == 1) {
                    outf[(size_t)row * N + col] = res[(size_t)row * N + col] + v;
                } else if constexpr (EPI == 2) {
                    ob0[(size_t)row * N + col] = (bf16_t)fmaxf(v + bias[col], 0.f);
                } else {
                    outf[(size_t)row * N + col] = res[(size_t)row * N + col] + v + bias[col];
                }
            }
}

// ---------------- flash attention (causal), 4 waves x 16 q-rows, KV tile 64 ----------------
__global__ __launch_bounds__(256, 2)
void attn_flash(const bf16_t* __restrict__ Q, const bf16_t* __restrict__ Kb,
                const bf16_t* __restrict__ VT, bf16_t* __restrict__ O) {
    const int tid = threadIdx.x, lane = tid & 63, w = tid >> 6;
    const int qbase = blockIdx.x << 6;
    __shared__ __align__(16) bf16_t P[4][16 * 64];
    const int l15 = lane & 15, hi = lane >> 4;
    const int koff = hi * 8;
    const int qrowA = qbase + w * 16 + l15;
    const bf16x8 qf0 = *(const bf16x8*)(Q + qrowA * 64 + koff);
    const bf16x8 qf1 = *(const bf16x8*)(Q + qrowA * 64 + 32 + koff);

    float m_run[4], l_run[4];
    f32x4 oacc[4];
#pragma unroll
    for (int r = 0; r < 4; ++r) { m_run[r] = -1e30f; l_run[r] = 0.f; }
#pragma unroll
    for (int d = 0; d < 4; ++d) oacc[d] = (f32x4){0.f, 0.f, 0.f, 0.f};

    const int nt = blockIdx.x + 1;
    for (int t = 0; t < nt; ++t) {
        const int kv0 = t << 6;
        f32x4 s[4];
#pragma unroll
        for (int ni = 0; ni < 4; ++ni) s[ni] = (f32x4){0.f, 0.f, 0.f, 0.f};
#pragma unroll
        for (int ni = 0; ni < 4; ++ni) {
            const bf16_t* kp = Kb + (kv0 + ni * 16 + l15) * 64 + koff;
            bf16x8 kf0 = *(const bf16x8*)(kp);
            bf16x8 kf1 = *(const bf16x8*)(kp + 32);
            s[ni] = __builtin_amdgcn_mfma_f32_16x16x32_bf16(qf0, kf0, s[ni], 0, 0, 0);
            s[ni] = __builtin_amdgcn_mfma_f32_16x16x32_bf16(qf1, kf1, s[ni], 0, 0, 0);
        }
        if (t == nt - 1) {  // diagonal tile: causal mask
#pragma unroll
            for (int ni = 0; ni < 4; ++ni)
#pragma unroll
                for (int r = 0; r < 4; ++r) {
                    const int col = kv0 + ni * 16 + l15;
                    const int row = qbase + w * 16 + hi * 4 + r;
                    if (col > row) s[ni][r] = -1e30f;
                }
        }
        float pv[4][4], alpha[4];
#pragma unroll
        for (int r = 0; r < 4; ++r) {
            float vm = fmaxf(fmaxf(s[0][r], s[1][r]), fmaxf(s[2][r], s[3][r]));
            vm = fmaxf(vm, __shfl_xor(vm, 1));
            vm = fmaxf(vm, __shfl_xor(vm, 2));
            vm = fmaxf(vm, __shfl_xor(vm, 4));
            vm = fmaxf(vm, __shfl_xor(vm, 8));
            const float mnew = fmaxf(m_run[r], vm);
            float sum = 0.f;
#pragma unroll
            for (int ni = 0; ni < 4; ++ni) {
                float p = __expf(s[ni][r] - mnew);
                pv[ni][r] = p; sum += p;
            }
            sum += __shfl_xor(sum, 1); sum += __shfl_xor(sum, 2);
            sum += __shfl_xor(sum, 4); sum += __shfl_xor(sum, 8);
            alpha[r] = __expf(m_run[r] - mnew);
            l_run[r] = l_run[r] * alpha[r] + sum;
            m_run[r] = mnew;
        }
#pragma unroll
        for (int d = 0; d < 4; ++d)
#pragma unroll
            for (int r = 0; r < 4; ++r) oacc[d][r] *= alpha[r];
        // C-layout -> A-layout redistribution through LDS
#pragma unroll
        for (int ni = 0; ni < 4; ++ni)
#pragma unroll
            for (int r = 0; r < 4; ++r)
                P[w][(hi * 4 + r) * 64 + ni * 16 + l15] = (bf16_t)pv[ni][r];
        __syncthreads();
#pragma unroll
        for (int ks = 0; ks < 2; ++ks) {
            bf16x8 pf = *(const bf16x8*)(&P[w][l15 * 64 + ks * 32 + koff]);
#pragma unroll
            for (int d = 0; d < 4; ++d) {
                bf16x8 vf = *(const bf16x8*)(VT + (size_t)(d * 16 + l15) * T_SEQ + kv0 + ks * 32 + koff);
                oacc[d] = __builtin_amdgcn_mfma_f32_16x16x32_bf16(pf, vf, oacc[d], 0, 0, 0);
            }
        }
        __syncthreads();
    }
#pragma unroll
    for (int d = 0; d < 4; ++d)
#pragma unroll
        for (int r = 0; r < 4; ++r) {
            const int row = qbase + w * 16 + hi * 4 + r;
            O[row * 64 + d * 16 + l15] = (bf16_t)(oacc[d][r] / l_run[r]);
        }
}

// ---------------- row LayerNorm (1024 cols), optional bf16 twin output ----------------
__global__ __launch_bounds__(256)
void ln_fused(const float* __restrict__ in, const float* __restrict__ g,
              const float* __restrict__ b, float* __restrict__ o32,
              bf16_t* __restrict__ o16) {
    const int row = blockIdx.x, tid = threadIdx.x;
    const float4 v = ((const float4*)(in + (size_t)row * NE))[tid];
    float s = v.x + v.y + v.z + v.w;
    float ss = v.x * v.x + v.y * v.y + v.z * v.z + v.w * v.w;
#pragma unroll
    for (int off = 1; off < 64; off <<= 1) {
        s  += __shfl_xor(s, off);
        ss += __shfl_xor(ss, off);
    }
    __shared__ float red[8];
    const int wv = tid >> 6, lane = tid & 63;
    if (lane == 0) { red[wv] = s; red[4 + wv] = ss; }
    __syncthreads();
    s  = red[0] + red[1] + red[2] + red[3];
    ss = red[4] + red[5] + red[6] + red[7];
    const float mu = s * (1.f / NE);
    const float rstd = rsqrtf(ss * (1.f / NE) - mu * mu + 1e-5f);
    const float4 gg = ((const float4*)g)[tid];
    const float4 bb = ((const float4*)b)[tid];
    float4 o;
    o.x = (v.x - mu) * rstd * gg.x + bb.x;
    o.y = (v.y - mu) * rstd * gg.y + bb.y;
    o.z = (v.z - mu) * rstd * gg.z + bb.z;
    o.w = (v.w - mu) * rstd * gg.w + bb.w;
    if (o32) ((float4*)(o32 + (size_t)row * NE))[tid] = o;
    if (o16) {
        bf16x4 h;
        h[0] = (bf16_t)o.x; h[1] = (bf16_t)o.y; h[2] = (bf16_t)o.z; h[3] = (bf16_t)o.w;
        *(bf16x4*)(o16 + (size_t)row * NE + tid * 4) = h;
    }
}

extern "C" void kernel_launch(void* const* d_in, const int* in_sizes, int n_in,
                              void* d_out, int out_size, void* d_ws, size_t ws_size,
                              hipStream_t stream) {
    (void)in_sizes; (void)n_in; (void)out_size; (void)ws_size;
    const float* x   = (const float*)d_in[0];
    const float* Wk  = (const float*)d_in[1];
    const float* Wq  = (const float*)d_in[2];
    const float* Wv  = (const float*)d_in[3];
    const float* Wp  = (const float*)d_in[4];
    const float* W1  = (const float*)d_in[5];
    const float* b1  = (const float*)d_in[6];
    const float* W2  = (const float*)d_in[7];
    const float* b2  = (const float*)d_in[8];
    const float* g1  = (const float*)d_in[9];
    const float* be1 = (const float*)d_in[10];
    const float* g2  = (const float*)d_in[11];
    const float* be2 = (const float*)d_in[12];
    float* out = (float*)d_out;

    char* ws = (char*)d_ws;
    bf16_t* xb   = (bf16_t*)(ws);                    // 16 MiB  x bf16
    bf16_t* x1b  = (bf16_t*)(ws + 16777216);         // 16 MiB  x1 bf16
    bf16_t* hb   = (bf16_t*)(ws + 33554432);         // 64 MiB  hidden bf16
    bf16_t* W1t  = (bf16_t*)(ws + 100663296);        // 8 MiB
    bf16_t* W2t  = (bf16_t*)(ws + 109051904);        // 8 MiB
    bf16_t* Wkqv = (bf16_t*)(ws + 117440512);        // 512 KiB (256x1024)
    bf16_t* WpT  = (bf16_t*)(ws + 117964800);        // 128 KiB
    bf16_t* kb   = (bf16_t*)(ws + 118095872);        // 1 MiB
    bf16_t* qb   = (bf16_t*)(ws + 119144448);        // 1 MiB
    bf16_t* vT   = (bf16_t*)(ws + 120193024);        // 1 MiB (64 x 8192)
    bf16_t* a0   = (bf16_t*)(ws + 121241600);        // 1 MiB attn out
    float*  r1   = (float*)(ws + 122290176);         // 32 MiB residual1 / x1
    float*  r2   = (float*)(ws + 155844608);         // 32 MiB residual2

    cast_f32_bf16<<<8192, 256, 0, stream>>>(x, xb, 2097152);
    build_wkqv<<<1024, 256, 0, stream>>>(Wk, Wq, Wv, Wkqv);
    tcast<<<dim3(16, 1), 256, 0, stream>>>(Wp, WpT, 64, 1024);
    tcast<<<dim3(64, 16), 256, 0, stream>>>(W1, W1t, 1024, 4096);
    tcast<<<dim3(16, 64), 256, 0, stream>>>(W2, W2t, 4096, 1024);

    // k,q,v projections (N padded to 256)
    gemm_bt<0><<<64 * 2, 256, 0, stream>>>(xb, Wkqv, 8192, 256, 1024,
                                           nullptr, kb, qb, vT, nullptr, nullptr);
    // causal flash attention
    attn_flash<<<128, 256, 0, stream>>>(qb, kb, vT, a0);
    // proj + residual: r1 = x + a0 @ Wp
    gemm_bt<1><<<64 * 8, 256, 0, stream>>>(a0, WpT, 8192, 1024, 64,
                                           r1, nullptr, nullptr, nullptr, x, nullptr);
    // x1 = LN(r1)  (in-place fp32) + bf16 twin
    ln_fused<<<8192, 256, 0, stream>>>(r1, g1, be1, r1, x1b);
    // h = relu(x1 @ W1 + b1)
    gemm_bt<2><<<64 * 32, 256, 0, stream>>>(x1b, W1t, 8192, 4096, 1024,
                                            nullptr, hb, nullptr, nullptr, nullptr, b1);
    // r2 = x1 + h @ W2 + b2
    gemm_bt<3><<<64 * 8, 256, 0, stream>>>(hb, W2t, 8192, 1024, 4096,
                                           r2, nullptr, nullptr, nullptr, r1, b2);
    // out = LN(r2)
    ln_fused<<<8192, 256, 0, stream>>>(r2, g2, be2, out, nullptr);
}

// Round 2
// 431.065 us; speedup vs baseline: 1.4352x; 1.4352x over previous
//
#include <hip/hip_runtime.h>
#include <hip/hip_bf16.h>

#define T_SEQ 8192
#define NE 1024
#define FF 4096

typedef __bf16 bf16_t;
typedef __bf16 bf16x8 __attribute__((ext_vector_type(8)));
typedef __bf16 bf16x4 __attribute__((ext_vector_type(4)));
typedef float f32x4 __attribute__((ext_vector_type(4)));

__device__ __forceinline__ void gll16(const void* g, void* l) {
    __builtin_amdgcn_global_load_lds(
        (const __attribute__((address_space(1))) void*)g,
        (__attribute__((address_space(3))) void*)l, 16, 0, 0);
}

// ---------------- elementwise cast fp32 -> bf16 (x4 per thread) ----------------
__global__ __launch_bounds__(256) void cast_f32_bf16(const float* __restrict__ in,
                                                     bf16_t* __restrict__ out, int n4) {
    int i = blockIdx.x * 256 + threadIdx.x;
    if (i >= n4) return;
    float4 v = ((const float4*)in)[i];
    bf16x4 h;
    h[0] = (bf16_t)v.x; h[1] = (bf16_t)v.y; h[2] = (bf16_t)v.z; h[3] = (bf16_t)v.w;
    ((bf16x4*)out)[i] = h;
}

// ---------------- build packed [Wk | Wq*0.125 | Wv | 0pad] as (256 x 1024) bf16, N-major ----------------
__global__ __launch_bounds__(256) void build_wkqv(const float* __restrict__ Wk,
                                                  const float* __restrict__ Wq,
                                                  const float* __restrict__ Wv,
                                                  bf16_t* __restrict__ out) {
    int idx = blockIdx.x * 256 + threadIdx.x;   // over 256*1024
    int n  = idx >> 10;   // 0..255  (output head-col)
    int kk = idx & 1023;  // 0..1023 (embd)
    float v = 0.f;
    if (n < 64)       v = Wk[kk * 64 + n];
    else if (n < 128) v = Wq[kk * 64 + (n - 64)] * 0.125f;  // fold 1/sqrt(hs)
    else if (n < 192) v = Wv[kk * 64 + (n - 128)];
    out[idx] = (bf16_t)v;
}

// ---------------- tiled transpose + cast: in (R x C) f32 -> out (C x R) bf16 ----------------
__global__ __launch_bounds__(256) void tcast(const float* __restrict__ in,
                                             bf16_t* __restrict__ out, int R, int C) {
    __shared__ bf16_t tl[64][66];
    const int bc = blockIdx.x << 6, br = blockIdx.y << 6;
    const int tx = threadIdx.x & 63, ty = threadIdx.x >> 6;
#pragma unroll
    for (int j = 0; j < 16; ++j) {
        const int r = ty + j * 4;
        tl[r][tx] = (bf16_t)in[(size_t)(br + r) * C + bc + tx];
    }
    __syncthreads();
#pragma unroll
    for (int j = 0; j < 16; ++j) {
        const int r = ty + j * 4;
        out[(size_t)(bc + r) * R + br + tx] = tl[tx][r];
    }
}

// ---------------- main GEMM: C(MxN) = A(MxK,bf16) @ Bt(NxK,bf16)^T, templated epilogue ----
template <int EPI>
__global__ __launch_bounds__(256, 2)
void gemm_bt(const bf16_t* __restrict__ A, const bf16_t* __restrict__ Bt,
             int M, int N, int K,
             float* __restrict__ outf,
             bf16_t* __restrict__ ob0, bf16_t* __restrict__ ob1, bf16_t* __restrict__ ob2,
             const float* __restrict__ res, const float* __restrict__ bias) {
    const int tid  = threadIdx.x;
    const int lane = tid & 63;
    const int tiles_n = N >> 7;
    const int tm = blockIdx.x / tiles_n;
    const int tn = blockIdx.x % tiles_n;
    const int brow = tm << 7, bcol = tn << 7;

    __shared__ __align__(16) bf16_t As[128 * 32];
    __shared__ __align__(16) bf16_t Bs[128 * 32];

    const int c1 = tid, c2 = tid + 256;
    const int s1 = (((c1 & 3) ^ ((c1 >> 3) & 3)) * 8);
    const int s2 = (((c2 & 3) ^ ((c2 >> 3) & 3)) * 8);
    const bf16_t* gA1 = A + (size_t)(brow + (c1 >> 2)) * K + s1;
    const bf16_t* gA2 = A + (size_t)(brow + (c2 >> 2)) * K + s2;
    const bf16_t* gB1 = Bt + (size_t)(bcol + (c1 >> 2)) * K + s1;
    const bf16_t* gB2 = Bt + (size_t)(bcol + (c2 >> 2)) * K + s2;
    bf16_t* lA1 = As + c1 * 8; bf16_t* lA2 = As + c2 * 8;
    bf16_t* lB1 = Bs + c1 * 8; bf16_t* lB2 = Bs + c2 * 8;

    const int wv = tid >> 6;
    const int wr = (wv >> 1) * 64, wc = (wv & 1) * 64;
    const int arow  = wr + (lane & 15);
    const int brf   = wc + (lane & 15);
    const int koff = (((lane >> 4) ^ ((lane >> 1) & 3)) * 8);

    f32x4 acc[4][4];
#pragma unroll
    for (int i = 0; i < 4; ++i)
#pragma unroll
        for (int j = 0; j < 4; ++j) acc[i][j] = (f32x4){0.f, 0.f, 0.f, 0.f};

    for (int k0 = 0; k0 < K; k0 += 32) {
        gll16(gA1, lA1); gll16(gA2, lA2);
        gll16(gB1, lB1); gll16(gB2, lB2);
        gA1 += 32; gA2 += 32; gB1 += 32; gB2 += 32;
        __syncthreads();
        bf16x8 af[4], bfr[4];
#pragma unroll
        for (int mi = 0; mi < 4; ++mi)
            af[mi] = *(const bf16x8*)(As + (arow + mi * 16) * 32 + koff);
#pragma unroll
        for (int ni = 0; ni < 4; ++ni)
            bfr[ni] = *(const bf16x8*)(Bs + (brf + ni * 16) * 32 + koff);
#pragma unroll
        for (int mi = 0; mi < 4; ++mi)
#pragma unroll
            for (int ni = 0; ni < 4; ++ni)
                acc[mi][ni] = __builtin_amdgcn_mfma_f32_16x16x32_bf16(
                    af[mi], bfr[ni], acc[mi][ni], 0, 0, 0);
        __syncthreads();
    }

    const int r0 = brow + wr + ((lane >> 4) << 2);
    const int c0 = bcol + wc + (lane & 15);
#pragma unroll
    for (int mi = 0; mi < 4; ++mi)
#pragma unroll
        for (int ni = 0; ni < 4; ++ni)
#pragma unroll
            for (int r = 0; r < 4; ++r) {
                const int row = r0 + mi * 16 + r;
                const int col = c0 + ni * 16;
                const float v = acc[mi][ni][r];
                if constexpr (EPI == 0) {
                    if (col < 64)       ob0[row * 64 + col] = (bf16_t)v;             // k
                    else if (col < 128) ob1[row * 64 + (col - 64)] = (bf16_t)v;      // q (pre-scaled)
                    else if (col < 192) ob2[(size_t)(col - 128) * T_SEQ + row] = (bf16_t)v; // v^T
                } else if constexpr (EPI == 1) {
                    outf[(size_t)row * N + col] = res[(size_t)row * N + col] + v;
                } else if constexpr (EPI == 2) {
                    ob0[(size_t)row * N + col] = (bf16_t)fmaxf(v + bias[col], 0.f);
                } else {
                    outf[(size_t)row * N + col] = res[(size_t)row * N + col] + v + bias[col];
                }
            }
}

// ---------------- split-KV flash attention partials ----------------
// 4352 jobs, one per wave. Job -> (qi [16-row q-subtile 0..511], chunk [8 kv-tiles]).
// Band a = g/8 (g = qi/4 diag tile): jobs base 16a(a+1), band = 32(a+1) jobs.
// Writes unnormalized o[16][64] f32 + m[16] + l[16] per job.
__global__ __launch_bounds__(256)
void attn_partial(const bf16_t* __restrict__ Q, const bf16_t* __restrict__ Kb,
                  const bf16_t* __restrict__ VT,
                  float* __restrict__ po, float* __restrict__ pml) {
    const int tid = threadIdx.x, lane = tid & 63, w = tid >> 6;
    const int j = blockIdx.x * 4 + w;           // job id, 0..4351

    // decode job -> (a, qi, chunk)
    int a = 0;
    while (j >= 16 * (a + 1) * (a + 2)) ++a;    // a in 0..15
    const int r_in = j - 16 * a * (a + 1);
    const int idx = r_in / (a + 1);             // 0..31
    const int chunk = r_in - idx * (a + 1);     // 0..a
    const int g = a * 8 + (idx >> 2);           // diag kv-tile 0..127
    const int qi = g * 4 + (idx & 3);           // q-subtile 0..511

    __shared__ __align__(16) bf16_t P[4][16 * 64];
    const int l15 = lane & 15, hi = lane >> 4;
    const int koff = hi * 8;
    const int qrow = qi * 16 + l15;
    const bf16x8 qf0 = *(const bf16x8*)(Q + qrow * 64 + koff);
    const bf16x8 qf1 = *(const bf16x8*)(Q + qrow * 64 + 32 + koff);

    float m_run[4], l_run[4];
    f32x4 oacc[4];
#pragma unroll
    for (int r = 0; r < 4; ++r) { m_run[r] = -1e30f; l_run[r] = 0.f; }
#pragma unroll
    for (int d = 0; d < 4; ++d) oacc[d] = (f32x4){0.f, 0.f, 0.f, 0.f};

    const int t0 = chunk * 8;
    const int t1 = min(t0 + 8, g + 1);
    for (int t = t0; t < t1; ++t) {
        const int kv0 = t << 6;
        f32x4 s[4];
#pragma unroll
        for (int ni = 0; ni < 4; ++ni) s[ni] = (f32x4){0.f, 0.f, 0.f, 0.f};
#pragma unroll
        for (int ni = 0; ni < 4; ++ni) {
            const bf16_t* kp = Kb + (kv0 + ni * 16 + l15) * 64 + koff;
            bf16x8 kf0 = *(const bf16x8*)(kp);
            bf16x8 kf1 = *(const bf16x8*)(kp + 32);
            s[ni] = __builtin_amdgcn_mfma_f32_16x16x32_bf16(qf0, kf0, s[ni], 0, 0, 0);
            s[ni] = __builtin_amdgcn_mfma_f32_16x16x32_bf16(qf1, kf1, s[ni], 0, 0, 0);
        }
        if (t == g) {  // diagonal tile: causal mask
#pragma unroll
            for (int ni = 0; ni < 4; ++ni)
#pragma unroll
                for (int r = 0; r < 4; ++r) {
                    const int col = kv0 + ni * 16 + l15;
                    const int row = qi * 16 + hi * 4 + r;
                    if (col > row) s[ni][r] = -1e30f;
                }
        }
        float pv[4][4], alpha[4];
#pragma unroll
        for (int r = 0; r < 4; ++r) {
            float vm = fmaxf(fmaxf(s[0][r], s[1][r]), fmaxf(s[2][r], s[3][r]));
            vm = fmaxf(vm, __shfl_xor(vm, 1));
            vm = fmaxf(vm, __shfl_xor(vm, 2));
            vm = fmaxf(vm, __shfl_xor(vm, 4));
            vm = fmaxf(vm, __shfl_xor(vm, 8));
            const float mnew = fmaxf(m_run[r], vm);
            float sum = 0.f;
#pragma unroll
            for (int ni = 0; ni < 4; ++ni) {
                float p = __expf(s[ni][r] - mnew);
                pv[ni][r] = p; sum += p;
            }
            sum += __shfl_xor(sum, 1); sum += __shfl_xor(sum, 2);
            sum += __shfl_xor(sum, 4); sum += __shfl_xor(sum, 8);
            alpha[r] = __expf(m_run[r] - mnew);
            l_run[r] = l_run[r] * alpha[r] + sum;
            m_run[r] = mnew;
        }
#pragma unroll
        for (int d = 0; d < 4; ++d)
#pragma unroll
            for (int r = 0; r < 4; ++r) oacc[d][r] *= alpha[r];
        // C-layout -> A-layout redistribution through per-wave LDS (no __syncthreads:
        // waves have divergent trip counts; wave-local ds ordering via lgkmcnt)
        asm volatile("s_waitcnt lgkmcnt(0)" ::: "memory");
#pragma unroll
        for (int ni = 0; ni < 4; ++ni)
#pragma unroll
            for (int r = 0; r < 4; ++r)
                P[w][(hi * 4 + r) * 64 + ni * 16 + l15] = (bf16_t)pv[ni][r];
        asm volatile("s_waitcnt lgkmcnt(0)" ::: "memory");
        __builtin_amdgcn_sched_barrier(0);
#pragma unroll
        for (int ks = 0; ks < 2; ++ks) {
            bf16x8 pf = *(const bf16x8*)(&P[w][l15 * 64 + ks * 32 + koff]);
#pragma unroll
            for (int d = 0; d < 4; ++d) {
                bf16x8 vf = *(const bf16x8*)(VT + (size_t)(d * 16 + l15) * T_SEQ + kv0 + ks * 32 + koff);
                oacc[d] = __builtin_amdgcn_mfma_f32_16x16x32_bf16(pf, vf, oacc[d], 0, 0, 0);
            }
        }
    }
    // store partial: o unnormalized, m, l
#pragma unroll
    for (int d = 0; d < 4; ++d)
#pragma unroll
        for (int r = 0; r < 4; ++r)
            po[(size_t)j * 1024 + (hi * 4 + r) * 64 + d * 16 + l15] = oacc[d][r];
    if (l15 == 0) {
#pragma unroll
        for (int r = 0; r < 4; ++r) {
            pml[(size_t)j * 32 + hi * 4 + r] = m_run[r];
            pml[(size_t)j * 32 + 16 + hi * 4 + r] = l_run[r];
        }
    }
}

// ---------------- combine partials: one wave per q-subtile ----------------
__global__ __launch_bounds__(64)
void attn_reduce(const float* __restrict__ po, const float* __restrict__ pml,
                 bf16_t* __restrict__ O) {
    const int qi = blockIdx.x;        // 0..511
    const int lane = threadIdx.x;     // d = lane
    const int g = qi >> 2;
    const int a = g >> 3;
    const int idx = ((g & 7) << 2) | (qi & 3);
    const int base = 16 * a * (a + 1) + idx * (a + 1);
    const int cnt = a + 1;

    for (int row = 0; row < 16; ++row) {
        float M = -1e30f;
        for (int i = 0; i < cnt; ++i)
            M = fmaxf(M, pml[(size_t)(base + i) * 32 + row]);
        float L = 0.f, o = 0.f;
        for (int i = 0; i < cnt; ++i) {
            const float m = pml[(size_t)(base + i) * 32 + row];
            const float l = pml[(size_t)(base + i) * 32 + 16 + row];
            const float wgt = __expf(m - M);
            L += l * wgt;
            o += po[(size_t)(base + i) * 1024 + row * 64 + lane] * wgt;
        }
        O[(size_t)(qi * 16 + row) * 64 + lane] = (bf16_t)(o / L);
    }
}

// ---------------- row LayerNorm (1024 cols), optional bf16 twin output ----------------
__global__ __launch_bounds__(256)
void ln_fused(const float* __restrict__ in, const float* __restrict__ g,
              const float* __restrict__ b, float* __restrict__ o32,
              bf16_t* __restrict__ o16) {
    const int row = blockIdx.x, tid = threadIdx.x;
    const float4 v = ((const float4*)(in + (size_t)row * NE))[tid];
    float s = v.x + v.y + v.z + v.w;
    float ss = v.x * v.x + v.y * v.y + v.z * v.z + v.w * v.w;
#pragma unroll
    for (int off = 1; off < 64; off <<= 1) {
        s  += __shfl_xor(s, off);
        ss += __shfl_xor(ss, off);
    }
    __shared__ float red[8];
    const int wv = tid >> 6, lane = tid & 63;
    if (lane == 0) { red[wv] = s; red[4 + wv] = ss; }
    __syncthreads();
    s  = red[0] + red[1] + red[2] + red[3];
    ss = red[4] + red[5] + red[6] + red[7];
    const float mu = s * (1.f / NE);
    const float rstd = rsqrtf(ss * (1.f / NE) - mu * mu + 1e-5f);
    const float4 gg = ((const float4*)g)[tid];
    const float4 bb = ((const float4*)b)[tid];
    float4 o;
    o.x = (v.x - mu) * rstd * gg.x + bb.x;
    o.y = (v.y - mu) * rstd * gg.y + bb.y;
    o.z = (v.z - mu) * rstd * gg.z + bb.z;
    o.w = (v.w - mu) * rstd * gg.w + bb.w;
    if (o32) ((float4*)(o32 + (size_t)row * NE))[tid] = o;
    if (o16) {
        bf16x4 h;
        h[0] = (bf16_t)o.x; h[1] = (bf16_t)o.y; h[2] = (bf16_t)o.z; h[3] = (bf16_t)o.w;
        *(bf16x4*)(o16 + (size_t)row * NE + tid * 4) = h;
    }
}

extern "C" void kernel_launch(void* const* d_in, const int* in_sizes, int n_in,
                              void* d_out, int out_size, void* d_ws, size_t ws_size,
                              hipStream_t stream) {
    (void)in_sizes; (void)n_in; (void)out_size; (void)ws_size;
    const float* x   = (const float*)d_in[0];
    const float* Wk  = (const float*)d_in[1];
    const float* Wq  = (const float*)d_in[2];
    const float* Wv  = (const float*)d_in[3];
    const float* Wp  = (const float*)d_in[4];
    const float* W1  = (const float*)d_in[5];
    const float* b1  = (const float*)d_in[6];
    const float* W2  = (const float*)d_in[7];
    const float* b2  = (const float*)d_in[8];
    const float* g1  = (const float*)d_in[9];
    const float* be1 = (const float*)d_in[10];
    const float* g2  = (const float*)d_in[11];
    const float* be2 = (const float*)d_in[12];
    float* out = (float*)d_out;

    char* ws = (char*)d_ws;
    bf16_t* xb   = (bf16_t*)(ws);                    // 16 MiB  x bf16
    bf16_t* x1b  = (bf16_t*)(ws + 16777216);         // 16 MiB  x1 bf16
    bf16_t* hb   = (bf16_t*)(ws + 33554432);         // 64 MiB  hidden bf16 (FFN phase)
    float*  po   = (float*)(ws + 33554432);          // 17.8 MiB attn partials (attn phase, overlaps hb)
    float*  pml  = (float*)(ws + 33554432 + 18874368); // 0.6 MiB m/l partials
    bf16_t* W1t  = (bf16_t*)(ws + 100663296);        // 8 MiB
    bf16_t* W2t  = (bf16_t*)(ws + 109051904);        // 8 MiB
    bf16_t* Wkqv = (bf16_t*)(ws + 117440512);        // 512 KiB (256x1024)
    bf16_t* WpT  = (bf16_t*)(ws + 117964800);        // 128 KiB
    bf16_t* kb   = (bf16_t*)(ws + 118095872);        // 1 MiB
    bf16_t* qb   = (bf16_t*)(ws + 119144448);        // 1 MiB
    bf16_t* vT   = (bf16_t*)(ws + 120193024);        // 1 MiB (64 x 8192)
    bf16_t* a0   = (bf16_t*)(ws + 121241600);        // 1 MiB attn out
    float*  r1   = (float*)(ws + 122290176);         // 32 MiB residual1 / x1
    float*  r2   = (float*)(ws + 155844608);         // 32 MiB residual2

    cast_f32_bf16<<<8192, 256, 0, stream>>>(x, xb, 2097152);
    build_wkqv<<<1024, 256, 0, stream>>>(Wk, Wq, Wv, Wkqv);
    tcast<<<dim3(16, 1), 256, 0, stream>>>(Wp, WpT, 64, 1024);
    tcast<<<dim3(64, 16), 256, 0, stream>>>(W1, W1t, 1024, 4096);
    tcast<<<dim3(16, 64), 256, 0, stream>>>(W2, W2t, 4096, 1024);

    // k,q,v projections (N padded to 256)
    gemm_bt<0><<<64 * 2, 256, 0, stream>>>(xb, Wkqv, 8192, 256, 1024,
                                           nullptr, kb, qb, vT, nullptr, nullptr);
    // causal flash attention: split-KV partials + reduce
    attn_partial<<<1088, 256, 0, stream>>>(qb, kb, vT, po, pml);
    attn_reduce<<<512, 64, 0, stream>>>(po, pml, a0);
    // proj + residual: r1 = x + a0 @ Wp
    gemm_bt<1><<<64 * 8, 256, 0, stream>>>(a0, WpT, 8192, 1024, 64,
                                           r1, nullptr, nullptr, nullptr, x, nullptr);
    // x1 = LN(r1)  (in-place fp32) + bf16 twin
    ln_fused<<<8192, 256, 0, stream>>>(r1, g1, be1, r1, x1b);
    // h = relu(x1 @ W1 + b1)
    gemm_bt<2><<<64 * 32, 256, 0, stream>>>(x1b, W1t, 8192, 4096, 1024,
                                            nullptr, hb, nullptr, nullptr, nullptr, b1);
    // r2 = x1 + h @ W2 + b2
    gemm_bt<3><<<64 * 8, 256, 0, stream>>>(hb, W2t, 8192, 1024, 4096,
                                           r2, nullptr, nullptr, nullptr, r1, b2);
    // out = LN(r2)
    ln_fused<<<8192, 256, 0, stream>>>(r2, g2, be2, out, nullptr);
}

// Round 3
// 417.389 us; speedup vs baseline: 1.4822x; 1.0328x over previous
//
#include <hip/hip_runtime.h>
#include <hip/hip_bf16.h>

#define T_SEQ 8192
#define NE 1024
#define FF 4096

typedef __bf16 bf16_t;
typedef __bf16 bf16x8 __attribute__((ext_vector_type(8)));
typedef __bf16 bf16x4 __attribute__((ext_vector_type(4)));
typedef float f32x4 __attribute__((ext_vector_type(4)));

__device__ __forceinline__ void gll16(const void* g, void* l) {
    __builtin_amdgcn_global_load_lds(
        (const __attribute__((address_space(1))) void*)g,
        (__attribute__((address_space(3))) void*)l, 16, 0, 0);
}

// ---------------- elementwise cast fp32 -> bf16 (x4 per thread) ----------------
__global__ __launch_bounds__(256) void cast_f32_bf16(const float* __restrict__ in,
                                                     bf16_t* __restrict__ out, int n4) {
    int i = blockIdx.x * 256 + threadIdx.x;
    if (i >= n4) return;
    float4 v = ((const float4*)in)[i];
    bf16x4 h;
    h[0] = (bf16_t)v.x; h[1] = (bf16_t)v.y; h[2] = (bf16_t)v.z; h[3] = (bf16_t)v.w;
    ((bf16x4*)out)[i] = h;
}

// ---------------- build packed [Wk | Wq*0.125 | Wv | 0pad] as (256 x 1024) bf16, N-major ----------------
__global__ __launch_bounds__(256) void build_wkqv(const float* __restrict__ Wk,
                                                  const float* __restrict__ Wq,
                                                  const float* __restrict__ Wv,
                                                  bf16_t* __restrict__ out) {
    int idx = blockIdx.x * 256 + threadIdx.x;   // over 256*1024
    int n  = idx >> 10;   // 0..255  (output head-col)
    int kk = idx & 1023;  // 0..1023 (embd)
    float v = 0.f;
    if (n < 64)       v = Wk[kk * 64 + n];
    else if (n < 128) v = Wq[kk * 64 + (n - 64)] * 0.125f;  // fold 1/sqrt(hs)
    else if (n < 192) v = Wv[kk * 64 + (n - 128)];
    out[idx] = (bf16_t)v;
}

// ---------------- tiled transpose + cast: in (R x C) f32 -> out (C x R) bf16 ----------------
__global__ __launch_bounds__(256) void tcast(const float* __restrict__ in,
                                             bf16_t* __restrict__ out, int R, int C) {
    __shared__ bf16_t tl[64][66];
    const int bc = blockIdx.x << 6, br = blockIdx.y << 6;
    const int tx = threadIdx.x & 63, ty = threadIdx.x >> 6;
#pragma unroll
    for (int j = 0; j < 16; ++j) {
        const int r = ty + j * 4;
        tl[r][tx] = (bf16_t)in[(size_t)(br + r) * C + bc + tx];
    }
    __syncthreads();
#pragma unroll
    for (int j = 0; j < 16; ++j) {
        const int r = ty + j * 4;
        out[(size_t)(bc + r) * R + br + tx] = tl[tx][r];
    }
}

// ---------------- legacy 128x128 GEMM (kept for QKV + proj epilogues) ----------
template <int EPI>
__global__ __launch_bounds__(256, 2)
void gemm_bt(const bf16_t* __restrict__ A, const bf16_t* __restrict__ Bt,
             int M, int N, int K,
             float* __restrict__ outf,
             bf16_t* __restrict__ ob0, bf16_t* __restrict__ ob1, bf16_t* __restrict__ ob2,
             const float* __restrict__ res, const float* __restrict__ bias) {
    const int tid  = threadIdx.x;
    const int lane = tid & 63;
    const int tiles_n = N >> 7;
    const int tm = blockIdx.x / tiles_n;
    const int tn = blockIdx.x % tiles_n;
    const int brow = tm << 7, bcol = tn << 7;

    __shared__ __align__(16) bf16_t As[128 * 32];
    __shared__ __align__(16) bf16_t Bs[128 * 32];

    const int c1 = tid, c2 = tid + 256;
    const int s1 = (((c1 & 3) ^ ((c1 >> 3) & 3)) * 8);
    const int s2 = (((c2 & 3) ^ ((c2 >> 3) & 3)) * 8);
    const bf16_t* gA1 = A + (size_t)(brow + (c1 >> 2)) * K + s1;
    const bf16_t* gA2 = A + (size_t)(brow + (c2 >> 2)) * K + s2;
    const bf16_t* gB1 = Bt + (size_t)(bcol + (c1 >> 2)) * K + s1;
    const bf16_t* gB2 = Bt + (size_t)(bcol + (c2 >> 2)) * K + s2;
    bf16_t* lA1 = As + c1 * 8; bf16_t* lA2 = As + c2 * 8;
    bf16_t* lB1 = Bs + c1 * 8; bf16_t* lB2 = Bs + c2 * 8;

    const int wv = tid >> 6;
    const int wr = (wv >> 1) * 64, wc = (wv & 1) * 64;
    const int arow  = wr + (lane & 15);
    const int brf   = wc + (lane & 15);
    const int koff = (((lane >> 4) ^ ((lane >> 1) & 3)) * 8);

    f32x4 acc[4][4];
#pragma unroll
    for (int i = 0; i < 4; ++i)
#pragma unroll
        for (int j = 0; j < 4; ++j) acc[i][j] = (f32x4){0.f, 0.f, 0.f, 0.f};

    for (int k0 = 0; k0 < K; k0 += 32) {
        gll16(gA1, lA1); gll16(gA2, lA2);
        gll16(gB1, lB1); gll16(gB2, lB2);
        gA1 += 32; gA2 += 32; gB1 += 32; gB2 += 32;
        __syncthreads();
        bf16x8 af[4], bfr[4];
#pragma unroll
        for (int mi = 0; mi < 4; ++mi)
            af[mi] = *(const bf16x8*)(As + (arow + mi * 16) * 32 + koff);
#pragma unroll
        for (int ni = 0; ni < 4; ++ni)
            bfr[ni] = *(const bf16x8*)(Bs + (brf + ni * 16) * 32 + koff);
#pragma unroll
        for (int mi = 0; mi < 4; ++mi)
#pragma unroll
            for (int ni = 0; ni < 4; ++ni)
                acc[mi][ni] = __builtin_amdgcn_mfma_f32_16x16x32_bf16(
                    af[mi], bfr[ni], acc[mi][ni], 0, 0, 0);
        __syncthreads();
    }

    const int r0 = brow + wr + ((lane >> 4) << 2);
    const int c0 = bcol + wc + (lane & 15);
#pragma unroll
    for (int mi = 0; mi < 4; ++mi)
#pragma unroll
        for (int ni = 0; ni < 4; ++ni)
#pragma unroll
            for (int r = 0; r < 4; ++r) {
                const int row = r0 + mi * 16 + r;
                const int col = c0 + ni * 16;
                const float v = acc[mi][ni][r];
                if constexpr (EPI == 0) {
                    if (col < 64)       ob0[row * 64 + col] = (bf16_t)v;             // k
                    else if (col < 128) ob1[row * 64 + (col - 64)] = (bf16_t)v;      // q (pre-scaled)
                    else if (col < 192) ob2[(size_t)(col - 128) * T_SEQ + row] = (bf16_t)v; // v^T
                } else if constexpr (EPI == 1) {
                    outf[(size_t)row * N + col] = res[(size_t)row * N + col] + v;
                } else if constexpr (EPI == 2) {
                    ob0[(size_t)row * N + col] = (bf16_t)fmaxf(v + bias[col], 0.f);
                } else {
                    outf[(size_t)row * N + col] = res[(size_t)row * N + col] + v + bias[col];
                }
            }
}

// ---------------- 8-phase counted-vmcnt GEMM (T1+T2+T3+T4+T5), 8 waves ----------------
// C(MxN) = A(MxK) @ Bt(NxK)^T. Wave grid 2Mx4N, per-wave (BM/2)x(BN/4). BK=64.
// EPI 2: ob = bf16(relu(C + bias)); EPI 3: outf = res + C + bias.
template <int BM, int BN, int EPI>
__global__ __launch_bounds__(512, 2)
void gemm8p(const bf16_t* __restrict__ A, const bf16_t* __restrict__ Bt,
            int M, int N, int K,
            float* __restrict__ outf, bf16_t* __restrict__ ob,
            const float* __restrict__ res, const float* __restrict__ bias) {
    constexpr int MREP = BM / 32;        // per-wave 16-row fragments
    constexpr int NREP = BN / 64;
    constexpr int AGRP = BM / 64;        // 8KB gll groups per A k-tile
    constexpr int BGRP = BN / 64;
    constexpr int GLLS = AGRP + BGRP;    // gll ops per wave per k-tile

    __shared__ __align__(16) bf16_t sA[2][BM * 64];
    __shared__ __align__(16) bf16_t sB[2][BN * 64];

    const int tid = threadIdx.x, lane = tid & 63, w = tid >> 6;
    const int wm = w >> 2, wn = w & 3;

    // XCD-aware block swizzle (gridDim.x % 8 == 0 for all our shapes)
    const int nwg = gridDim.x;
    const int wg = (blockIdx.x & 7) * (nwg >> 3) + (blockIdx.x >> 3);
    const int tiles_n = N / BN;
    const int tm = wg / tiles_n, tn = wg % tiles_n;
    const int brow = tm * BM, bcol = tn * BN;

    // staging: thread tid handles 16B chunk (row = grp*64 + tid/8, slot16 = tid&7).
    // LDS dest linear; global source slot pre-swizzled by (row&7) (involution).
    const int srow = tid >> 3;
    const int scol = (tid & 7) ^ (srow & 7);
    const bf16_t* gA = A + (size_t)(brow + srow) * K + scol * 8;
    const bf16_t* gB = Bt + (size_t)(bcol + srow) * K + scol * 8;

    auto STAGE = [&](int p, int kt) {
        const bf16_t* a = gA + (size_t)kt * 64;
        const bf16_t* b = gB + (size_t)kt * 64;
#pragma unroll
        for (int g = 0; g < AGRP; ++g)
            gll16(a + (size_t)g * 64 * K, &sA[p][g * 4096 + tid * 8]);
#pragma unroll
        for (int g = 0; g < BGRP; ++g)
            gll16(b + (size_t)g * 64 * K, &sB[p][g * 4096 + tid * 8]);
    };
    auto WAIT_VM_G = []() {
        if constexpr (GLLS == 8) asm volatile("s_waitcnt vmcnt(8)" ::: "memory");
        else                     asm volatile("s_waitcnt vmcnt(6)" ::: "memory");
    };

    // read-side fragment addressing (swizzled): row&7 == lane&7 for all frag rows
    const int l15 = lane & 15, sq = lane >> 4, sx = lane & 7;
    const int arowb = (wm * (BM / 2) + l15) * 64;
    const int browb = (wn * (BN / 4) + l15) * 64;
    const int cks0 = ((sq) ^ sx) * 8;        // k-slice 0 slot16
    const int cks1 = ((4 | sq) ^ sx) * 8;    // k-slice 1 slot16

    f32x4 acc[MREP][NREP];
#pragma unroll
    for (int i = 0; i < MREP; ++i)
#pragma unroll
        for (int j = 0; j < NREP; ++j) acc[i][j] = (f32x4){0.f, 0.f, 0.f, 0.f};

    const int NT = K >> 6;   // k-tiles of 64 (NT even for all our shapes)
    STAGE(0, 0);
    STAGE(1, 1);
    WAIT_VM_G();
    __builtin_amdgcn_s_barrier();

    for (int t = 0; t < NT; t += 2) {
#pragma unroll
        for (int half = 0; half < 2; ++half) {
            const int p = half;           // static after unroll
            bf16x8 af[MREP], bfr[NREP];
            // ---- phase ks0 ----
#pragma unroll
            for (int m = 0; m < MREP; ++m)
                af[m] = *(const bf16x8*)(&sA[p][arowb + m * 1024 + cks0]);
#pragma unroll
            for (int n = 0; n < NREP; ++n)
                bfr[n] = *(const bf16x8*)(&sB[p][browb + n * 1024 + cks0]);
            __builtin_amdgcn_s_barrier();
            asm volatile("s_waitcnt lgkmcnt(0)" ::: "memory");
            __builtin_amdgcn_sched_barrier(0);
            __builtin_amdgcn_s_setprio(1);
#pragma unroll
            for (int m = 0; m < MREP; ++m)
#pragma unroll
                for (int n = 0; n < NREP; ++n)
                    acc[m][n] = __builtin_amdgcn_mfma_f32_16x16x32_bf16(
                        af[m], bfr[n], acc[m][n], 0, 0, 0);
            __builtin_amdgcn_s_setprio(0);
            // ---- phase ks1 ----
#pragma unroll
            for (int m = 0; m < MREP; ++m)
                af[m] = *(const bf16x8*)(&sA[p][arowb + m * 1024 + cks1]);
#pragma unroll
            for (int n = 0; n < NREP; ++n)
                bfr[n] = *(const bf16x8*)(&sB[p][browb + n * 1024 + cks1]);
            asm volatile("s_waitcnt lgkmcnt(0)" ::: "memory");
            __builtin_amdgcn_sched_barrier(0);
            __builtin_amdgcn_s_setprio(1);
#pragma unroll
            for (int m = 0; m < MREP; ++m)
#pragma unroll
                for (int n = 0; n < NREP; ++n)
                    acc[m][n] = __builtin_amdgcn_mfma_f32_16x16x32_bf16(
                        af[m], bfr[n], acc[m][n], 0, 0, 0);
            __builtin_amdgcn_s_setprio(0);
            __builtin_amdgcn_s_barrier();            // all waves done reading buf p
            if (t + 2 + half < NT) {
                STAGE(p, t + 2 + half);              // refill buf p with tile t+2
                WAIT_VM_G();                         // tile t+1 loads retired (mine)
            } else {
                asm volatile("s_waitcnt vmcnt(0)" ::: "memory");  // tail drain
            }
            __builtin_amdgcn_s_barrier();            // tile t+1 visible to all
        }
    }

    // epilogue: C/D layout col=lane&15, row=(lane>>4)*4+reg
    const int r0 = brow + wm * (BM / 2) + (sq << 2);
    const int c0 = bcol + wn * (BN / 4) + l15;
#pragma unroll
    for (int m = 0; m < MREP; ++m)
#pragma unroll
        for (int n = 0; n < NREP; ++n) {
            const int col = c0 + n * 16;
#pragma unroll
            for (int r = 0; r < 4; ++r) {
                const int row = r0 + m * 16 + r;
                const float v = acc[m][n][r];
                if constexpr (EPI == 2) {
                    ob[(size_t)row * N + col] = (bf16_t)fmaxf(v + bias[col], 0.f);
                } else {
                    outf[(size_t)row * N + col] = res[(size_t)row * N + col] + v + bias[col];
                }
            }
        }
}

// ---------------- split-KV flash attention partials ----------------
__global__ __launch_bounds__(256)
void attn_partial(const bf16_t* __restrict__ Q, const bf16_t* __restrict__ Kb,
                  const bf16_t* __restrict__ VT,
                  float* __restrict__ po, float* __restrict__ pml) {
    const int tid = threadIdx.x, lane = tid & 63, w = tid >> 6;
    const int j = blockIdx.x * 4 + w;           // job id, 0..4351

    int a = 0;
    while (j >= 16 * (a + 1) * (a + 2)) ++a;    // a in 0..15
    const int r_in = j - 16 * a * (a + 1);
    const int idx = r_in / (a + 1);             // 0..31
    const int chunk = r_in - idx * (a + 1);     // 0..a
    const int g = a * 8 + (idx >> 2);           // diag kv-tile 0..127
    const int qi = g * 4 + (idx & 3);           // q-subtile 0..511

    __shared__ __align__(16) bf16_t P[4][16 * 64];
    const int l15 = lane & 15, hi = lane >> 4;
    const int koff = hi * 8;
    const int qrow = qi * 16 + l15;
    const bf16x8 qf0 = *(const bf16x8*)(Q + qrow * 64 + koff);
    const bf16x8 qf1 = *(const bf16x8*)(Q + qrow * 64 + 32 + koff);

    float m_run[4], l_run[4];
    f32x4 oacc[4];
#pragma unroll
    for (int r = 0; r < 4; ++r) { m_run[r] = -1e30f; l_run[r] = 0.f; }
#pragma unroll
    for (int d = 0; d < 4; ++d) oacc[d] = (f32x4){0.f, 0.f, 0.f, 0.f};

    const int t0 = chunk * 8;
    const int t1 = min(t0 + 8, g + 1);
    for (int t = t0; t < t1; ++t) {
        const int kv0 = t << 6;
        f32x4 s[4];
#pragma unroll
        for (int ni = 0; ni < 4; ++ni) s[ni] = (f32x4){0.f, 0.f, 0.f, 0.f};
#pragma unroll
        for (int ni = 0; ni < 4; ++ni) {
            const bf16_t* kp = Kb + (kv0 + ni * 16 + l15) * 64 + koff;
            bf16x8 kf0 = *(const bf16x8*)(kp);
            bf16x8 kf1 = *(const bf16x8*)(kp + 32);
            s[ni] = __builtin_amdgcn_mfma_f32_16x16x32_bf16(qf0, kf0, s[ni], 0, 0, 0);
            s[ni] = __builtin_amdgcn_mfma_f32_16x16x32_bf16(qf1, kf1, s[ni], 0, 0, 0);
        }
        if (t == g) {
#pragma unroll
            for (int ni = 0; ni < 4; ++ni)
#pragma unroll
                for (int r = 0; r < 4; ++r) {
                    const int col = kv0 + ni * 16 + l15;
                    const int row = qi * 16 + hi * 4 + r;
                    if (col > row) s[ni][r] = -1e30f;
                }
        }
        float pv[4][4], alpha[4];
#pragma unroll
        for (int r = 0; r < 4; ++r) {
            float vm = fmaxf(fmaxf(s[0][r], s[1][r]), fmaxf(s[2][r], s[3][r]));
            vm = fmaxf(vm, __shfl_xor(vm, 1));
            vm = fmaxf(vm, __shfl_xor(vm, 2));
            vm = fmaxf(vm, __shfl_xor(vm, 4));
            vm = fmaxf(vm, __shfl_xor(vm, 8));
            const float mnew = fmaxf(m_run[r], vm);
            float sum = 0.f;
#pragma unroll
            for (int ni = 0; ni < 4; ++ni) {
                float p = __expf(s[ni][r] - mnew);
                pv[ni][r] = p; sum += p;
            }
            sum += __shfl_xor(sum, 1); sum += __shfl_xor(sum, 2);
            sum += __shfl_xor(sum, 4); sum += __shfl_xor(sum, 8);
            alpha[r] = __expf(m_run[r] - mnew);
            l_run[r] = l_run[r] * alpha[r] + sum;
            m_run[r] = mnew;
        }
#pragma unroll
        for (int d = 0; d < 4; ++d)
#pragma unroll
            for (int r = 0; r < 4; ++r) oacc[d][r] *= alpha[r];
        asm volatile("s_waitcnt lgkmcnt(0)" ::: "memory");
#pragma unroll
        for (int ni = 0; ni < 4; ++ni)
#pragma unroll
            for (int r = 0; r < 4; ++r)
                P[w][(hi * 4 + r) * 64 + ni * 16 + l15] = (bf16_t)pv[ni][r];
        asm volatile("s_waitcnt lgkmcnt(0)" ::: "memory");
        __builtin_amdgcn_sched_barrier(0);
#pragma unroll
        for (int ks = 0; ks < 2; ++ks) {
            bf16x8 pf = *(const bf16x8*)(&P[w][l15 * 64 + ks * 32 + koff]);
#pragma unroll
            for (int d = 0; d < 4; ++d) {
                bf16x8 vf = *(const bf16x8*)(VT + (size_t)(d * 16 + l15) * T_SEQ + kv0 + ks * 32 + koff);
                oacc[d] = __builtin_amdgcn_mfma_f32_16x16x32_bf16(pf, vf, oacc[d], 0, 0, 0);
            }
        }
    }
#pragma unroll
    for (int d = 0; d < 4; ++d)
#pragma unroll
        for (int r = 0; r < 4; ++r)
            po[(size_t)j * 1024 + (hi * 4 + r) * 64 + d * 16 + l15] = oacc[d][r];
    if (l15 == 0) {
#pragma unroll
        for (int r = 0; r < 4; ++r) {
            pml[(size_t)j * 32 + hi * 4 + r] = m_run[r];
            pml[(size_t)j * 32 + 16 + hi * 4 + r] = l_run[r];
        }
    }
}

// ---------------- combine partials: one wave per q-subtile ----------------
__global__ __launch_bounds__(64)
void attn_reduce(const float* __restrict__ po, const float* __restrict__ pml,
                 bf16_t* __restrict__ O) {
    const int qi = blockIdx.x;        // 0..511
    const int lane = threadIdx.x;     // d = lane
    const int g = qi >> 2;
    const int a = g >> 3;
    const int idx = ((g & 7) << 2) | (qi & 3);
    const int base = 16 * a * (a + 1) + idx * (a + 1);
    const int cnt = a + 1;

    for (int row = 0; row < 16; ++row) {
        float M = -1e30f;
        for (int i = 0; i < cnt; ++i)
            M = fmaxf(M, pml[(size_t)(base + i) * 32 + row]);
        float L = 0.f, o = 0.f;
        for (int i = 0; i < cnt; ++i) {
            const float m = pml[(size_t)(base + i) * 32 + row];
            const float l = pml[(size_t)(base + i) * 32 + 16 + row];
            const float wgt = __expf(m - M);
            L += l * wgt;
            o += po[(size_t)(base + i) * 1024 + row * 64 + lane] * wgt;
        }
        O[(size_t)(qi * 16 + row) * 64 + lane] = (bf16_t)(o / L);
    }
}

// ---------------- row LayerNorm (1024 cols), optional bf16 twin output ----------------
__global__ __launch_bounds__(256)
void ln_fused(const float* __restrict__ in, const float* __restrict__ g,
              const float* __restrict__ b, float* __restrict__ o32,
              bf16_t* __restrict__ o16) {
    const int row = blockIdx.x, tid = threadIdx.x;
    const float4 v = ((const float4*)(in + (size_t)row * NE))[tid];
    float s = v.x + v.y + v.z + v.w;
    float ss = v.x * v.x + v.y * v.y + v.z * v.z + v.w * v.w;
#pragma unroll
    for (int off = 1; off < 64; off <<= 1) {
        s  += __shfl_xor(s, off);
        ss += __shfl_xor(ss, off);
    }
    __shared__ float red[8];
    const int wv = tid >> 6, lane = tid & 63;
    if (lane == 0) { red[wv] = s; red[4 + wv] = ss; }
    __syncthreads();
    s  = red[0] + red[1] + red[2] + red[3];
    ss = red[4] + red[5] + red[6] + red[7];
    const float mu = s * (1.f / NE);
    const float rstd = rsqrtf(ss * (1.f / NE) - mu * mu + 1e-5f);
    const float4 gg = ((const float4*)g)[tid];
    const float4 bb = ((const float4*)b)[tid];
    float4 o;
    o.x = (v.x - mu) * rstd * gg.x + bb.x;
    o.y = (v.y - mu) * rstd * gg.y + bb.y;
    o.z = (v.z - mu) * rstd * gg.z + bb.z;
    o.w = (v.w - mu) * rstd * gg.w + bb.w;
    if (o32) ((float4*)(o32 + (size_t)row * NE))[tid] = o;
    if (o16) {
        bf16x4 h;
        h[0] = (bf16_t)o.x; h[1] = (bf16_t)o.y; h[2] = (bf16_t)o.z; h[3] = (bf16_t)o.w;
        *(bf16x4*)(o16 + (size_t)row * NE + tid * 4) = h;
    }
}

extern "C" void kernel_launch(void* const* d_in, const int* in_sizes, int n_in,
                              void* d_out, int out_size, void* d_ws, size_t ws_size,
                              hipStream_t stream) {
    (void)in_sizes; (void)n_in; (void)out_size; (void)ws_size;
    const float* x   = (const float*)d_in[0];
    const float* Wk  = (const float*)d_in[1];
    const float* Wq  = (const float*)d_in[2];
    const float* Wv  = (const float*)d_in[3];
    const float* Wp  = (const float*)d_in[4];
    const float* W1  = (const float*)d_in[5];
    const float* b1  = (const float*)d_in[6];
    const float* W2  = (const float*)d_in[7];
    const float* b2  = (const float*)d_in[8];
    const float* g1  = (const float*)d_in[9];
    const float* be1 = (const float*)d_in[10];
    const float* g2  = (const float*)d_in[11];
    const float* be2 = (const float*)d_in[12];
    float* out = (float*)d_out;

    char* ws = (char*)d_ws;
    bf16_t* xb   = (bf16_t*)(ws);                    // 16 MiB  x bf16
    bf16_t* x1b  = (bf16_t*)(ws + 16777216);         // 16 MiB  x1 bf16
    bf16_t* hb   = (bf16_t*)(ws + 33554432);         // 64 MiB  hidden bf16 (FFN phase)
    float*  po   = (float*)(ws + 33554432);          // 17.8 MiB attn partials (overlaps hb)
    float*  pml  = (float*)(ws + 33554432 + 18874368); // 0.6 MiB m/l partials
    bf16_t* W1t  = (bf16_t*)(ws + 100663296);        // 8 MiB
    bf16_t* W2t  = (bf16_t*)(ws + 109051904);        // 8 MiB
    bf16_t* Wkqv = (bf16_t*)(ws + 117440512);        // 512 KiB (256x1024)
    bf16_t* WpT  = (bf16_t*)(ws + 117964800);        // 128 KiB
    bf16_t* kb   = (bf16_t*)(ws + 118095872);        // 1 MiB
    bf16_t* qb   = (bf16_t*)(ws + 119144448);        // 1 MiB
    bf16_t* vT   = (bf16_t*)(ws + 120193024);        // 1 MiB (64 x 8192)
    bf16_t* a0   = (bf16_t*)(ws + 121241600);        // 1 MiB attn out
    float*  r1   = (float*)(ws + 122290176);         // 32 MiB residual1 / x1
    float*  r2   = (float*)(ws + 155844608);         // 32 MiB residual2

    cast_f32_bf16<<<8192, 256, 0, stream>>>(x, xb, 2097152);
    build_wkqv<<<1024, 256, 0, stream>>>(Wk, Wq, Wv, Wkqv);
    tcast<<<dim3(16, 1), 256, 0, stream>>>(Wp, WpT, 64, 1024);
    tcast<<<dim3(64, 16), 256, 0, stream>>>(W1, W1t, 1024, 4096);
    tcast<<<dim3(16, 64), 256, 0, stream>>>(W2, W2t, 4096, 1024);

    // k,q,v projections (N padded to 256)
    gemm_bt<0><<<64 * 2, 256, 0, stream>>>(xb, Wkqv, 8192, 256, 1024,
                                           nullptr, kb, qb, vT, nullptr, nullptr);
    // causal flash attention: split-KV partials + reduce
    attn_partial<<<1088, 256, 0, stream>>>(qb, kb, vT, po, pml);
    attn_reduce<<<512, 64, 0, stream>>>(po, pml, a0);
    // proj + residual: r1 = x + a0 @ Wp
    gemm_bt<1><<<64 * 8, 256, 0, stream>>>(a0, WpT, 8192, 1024, 64,
                                           r1, nullptr, nullptr, nullptr, x, nullptr);
    // x1 = LN(r1)  (in-place fp32) + bf16 twin
    ln_fused<<<8192, 256, 0, stream>>>(r1, g1, be1, r1, x1b);
    // h = relu(x1 @ W1 + b1)   [8-phase 256x256]
    gemm8p<256, 256, 2><<<512, 512, 0, stream>>>(x1b, W1t, 8192, 4096, 1024,
                                                 nullptr, hb, nullptr, b1);
    // r2 = x1 + h @ W2 + b2    [8-phase 128x256]
    gemm8p<128, 256, 3><<<256, 512, 0, stream>>>(hb, W2t, 8192, 1024, 4096,
                                                 r2, nullptr, r1, b2);
    // out = LN(r2)
    ln_fused<<<8192, 256, 0, stream>>>(r2, g2, be2, out, nullptr);
}

// Round 5
// 358.258 us; speedup vs baseline: 1.7268x; 1.1651x over previous
//
#include <hip/hip_runtime.h>
#include <hip/hip_bf16.h>

#define T_SEQ 8192
#define NE 1024
#define FF 4096

typedef __bf16 bf16_t;
typedef __bf16 bf16x8 __attribute__((ext_vector_type(8)));
typedef __bf16 bf16x4 __attribute__((ext_vector_type(4)));
typedef float f32x4 __attribute__((ext_vector_type(4)));

__device__ __forceinline__ void gll16(const void* g, void* l) {
    __builtin_amdgcn_global_load_lds(
        (const __attribute__((address_space(1))) void*)g,
        (__attribute__((address_space(3))) void*)l, 16, 0, 0);
}

// ---------------- elementwise cast fp32 -> bf16 (x4 per thread) ----------------
__global__ __launch_bounds__(256) void cast_f32_bf16(const float* __restrict__ in,
                                                     bf16_t* __restrict__ out, int n4) {
    int i = blockIdx.x * 256 + threadIdx.x;
    if (i >= n4) return;
    float4 v = ((const float4*)in)[i];
    bf16x4 h;
    h[0] = (bf16_t)v.x; h[1] = (bf16_t)v.y; h[2] = (bf16_t)v.z; h[3] = (bf16_t)v.w;
    ((bf16x4*)out)[i] = h;
}

// ---------------- build packed [Wk | Wq*0.125 | Wv | 0pad] as (256 x 1024) bf16, N-major ----------------
__global__ __launch_bounds__(256) void build_wkqv(const float* __restrict__ Wk,
                                                  const float* __restrict__ Wq,
                                                  const float* __restrict__ Wv,
                                                  bf16_t* __restrict__ out) {
    int idx = blockIdx.x * 256 + threadIdx.x;   // over 256*1024
    int n  = idx >> 10;   // 0..255  (output head-col)
    int kk = idx & 1023;  // 0..1023 (embd)
    float v = 0.f;
    if (n < 64)       v = Wk[kk * 64 + n];
    else if (n < 128) v = Wq[kk * 64 + (n - 64)] * 0.125f;  // fold 1/sqrt(hs)
    else if (n < 192) v = Wv[kk * 64 + (n - 128)];
    out[idx] = (bf16_t)v;
}

// ---------------- tiled transpose + cast: in (R x C) f32 -> out (C x R) bf16 ----------------
__global__ __launch_bounds__(256) void tcast(const float* __restrict__ in,
                                             bf16_t* __restrict__ out, int R, int C) {
    __shared__ bf16_t tl[64][66];
    const int bc = blockIdx.x << 6, br = blockIdx.y << 6;
    const int tx = threadIdx.x & 63, ty = threadIdx.x >> 6;
#pragma unroll
    for (int j = 0; j < 16; ++j) {
        const int r = ty + j * 4;
        tl[r][tx] = (bf16_t)in[(size_t)(br + r) * C + bc + tx];
    }
    __syncthreads();
#pragma unroll
    for (int j = 0; j < 16; ++j) {
        const int r = ty + j * 4;
        out[(size_t)(bc + r) * R + br + tx] = tl[tx][r];
    }
}

// ---------------- pack W (KxN f32 row-major) into MFMA B-frag layout ----------------
// out[((nf*KS + ksl)*64 + lane)*8 + j] = W[(ksl*32 + (lane>>4)*8 + j)*N + nf*16 + (lane&15)]
__global__ __launch_bounds__(256)
void pack_bfrag(const float* __restrict__ W, bf16_t* __restrict__ out, int N, int KS) {
    const int gid = blockIdx.x * 4 + (threadIdx.x >> 6);
    const int lane = threadIdx.x & 63;
    const int nf = gid / KS, ksl = gid - nf * KS;
    const int col = nf * 16 + (lane & 15);
    const size_t krow = (size_t)ksl * 32 + ((lane >> 4) << 3);
    bf16x8 v;
#pragma unroll
    for (int j = 0; j < 8; ++j)
        v[j] = (bf16_t)W[(krow + j) * N + col];
    *(bf16x8*)(out + (size_t)gid * 512 + lane * 8) = v;
}

// ---------------- legacy 128x128 GEMM (kept for QKV + proj epilogues) ----------
template <int EPI>
__global__ __launch_bounds__(256, 2)
void gemm_bt(const bf16_t* __restrict__ A, const bf16_t* __restrict__ Bt,
             int M, int N, int K,
             float* __restrict__ outf,
             bf16_t* __restrict__ ob0, bf16_t* __restrict__ ob1, bf16_t* __restrict__ ob2,
             const float* __restrict__ res, const float* __restrict__ bias) {
    const int tid  = threadIdx.x;
    const int lane = tid & 63;
    const int tiles_n = N >> 7;
    const int tm = blockIdx.x / tiles_n;
    const int tn = blockIdx.x % tiles_n;
    const int brow = tm << 7, bcol = tn << 7;

    __shared__ __align__(16) bf16_t As[128 * 32];
    __shared__ __align__(16) bf16_t Bs[128 * 32];

    const int c1 = tid, c2 = tid + 256;
    const int s1 = (((c1 & 3) ^ ((c1 >> 3) & 3)) * 8);
    const int s2 = (((c2 & 3) ^ ((c2 >> 3) & 3)) * 8);
    const bf16_t* gA1 = A + (size_t)(brow + (c1 >> 2)) * K + s1;
    const bf16_t* gA2 = A + (size_t)(brow + (c2 >> 2)) * K + s2;
    const bf16_t* gB1 = Bt + (size_t)(bcol + (c1 >> 2)) * K + s1;
    const bf16_t* gB2 = Bt + (size_t)(bcol + (c2 >> 2)) * K + s2;
    bf16_t* lA1 = As + c1 * 8; bf16_t* lA2 = As + c2 * 8;
    bf16_t* lB1 = Bs + c1 * 8; bf16_t* lB2 = Bs + c2 * 8;

    const int wv = tid >> 6;
    const int wr = (wv >> 1) * 64, wc = (wv & 1) * 64;
    const int arow  = wr + (lane & 15);
    const int brf   = wc + (lane & 15);
    const int koff = (((lane >> 4) ^ ((lane >> 1) & 3)) * 8);

    f32x4 acc[4][4];
#pragma unroll
    for (int i = 0; i < 4; ++i)
#pragma unroll
        for (int j = 0; j < 4; ++j) acc[i][j] = (f32x4){0.f, 0.f, 0.f, 0.f};

    for (int k0 = 0; k0 < K; k0 += 32) {
        gll16(gA1, lA1); gll16(gA2, lA2);
        gll16(gB1, lB1); gll16(gB2, lB2);
        gA1 += 32; gA2 += 32; gB1 += 32; gB2 += 32;
        __syncthreads();
        bf16x8 af[4], bfr[4];
#pragma unroll
        for (int mi = 0; mi < 4; ++mi)
            af[mi] = *(const bf16x8*)(As + (arow + mi * 16) * 32 + koff);
#pragma unroll
        for (int ni = 0; ni < 4; ++ni)
            bfr[ni] = *(const bf16x8*)(Bs + (brf + ni * 16) * 32 + koff);
#pragma unroll
        for (int mi = 0; mi < 4; ++mi)
#pragma unroll
            for (int ni = 0; ni < 4; ++ni)
                acc[mi][ni] = __builtin_amdgcn_mfma_f32_16x16x32_bf16(
                    af[mi], bfr[ni], acc[mi][ni], 0, 0, 0);
        __syncthreads();
    }

    const int r0 = brow + wr + ((lane >> 4) << 2);
    const int c0 = bcol + wc + (lane & 15);
#pragma unroll
    for (int mi = 0; mi < 4; ++mi)
#pragma unroll
        for (int ni = 0; ni < 4; ++ni)
#pragma unroll
            for (int r = 0; r < 4; ++r) {
                const int row = r0 + mi * 16 + r;
                const int col = c0 + ni * 16;
                const float v = acc[mi][ni][r];
                if constexpr (EPI == 0) {
                    if (col < 64)       ob0[row * 64 + col] = (bf16_t)v;             // k
                    else if (col < 128) ob1[row * 64 + (col - 64)] = (bf16_t)v;      // q (pre-scaled)
                    else if (col < 192) ob2[(size_t)(col - 128) * T_SEQ + row] = (bf16_t)v; // v^T
                } else if constexpr (EPI == 1) {
                    outf[(size_t)row * N + col] = res[(size_t)row * N + col] + v;
                } else if constexpr (EPI == 2) {
                    ob0[(size_t)row * N + col] = (bf16_t)fmaxf(v + bias[col], 0.f);
                } else {
                    outf[(size_t)row * N + col] = res[(size_t)row * N + col] + v + bias[col];
                }
            }
}

// ---------------- B-global GEMM v2 (hardened): named B regs, branch-free pipeline ----
// BM=BN=128, 4 waves 2x2, per-wave 64x64. A staged via gll into 16KB LDS (XOR-swizzled
// source), B-frags from pre-packed global into 16 NAMED registers, double-buffered.
// Sync discipline: every barrier/waitcnt pinned with sched_barrier(0) (rules #18/#19).
template <int EPI>
__global__ __launch_bounds__(256, 2)
void gemm_bg(const bf16_t* __restrict__ A, const bf16_t* __restrict__ Bp,
             int M, int N, int K,
             float* __restrict__ outf, bf16_t* __restrict__ ob,
             const float* __restrict__ res, const float* __restrict__ bias) {
    __shared__ __align__(16) bf16_t sA[128 * 64];
    const int tid = threadIdx.x, lane = tid & 63, w = tid >> 6;
    const int wm = w >> 1, wn = w & 1;

    const int nwg = gridDim.x;                       // %8 == 0 for our shapes
    const int wgid = (blockIdx.x & 7) * (nwg >> 3) + (blockIdx.x >> 3);
    const int tiles_n = N >> 7;
    const int tm = wgid / tiles_n, tn = wgid % tiles_n;
    const int brow = tm << 7, bcol = tn << 7;

    // A staging: thread -> 16B chunk, row = srow (+g*32), slot16 = tid&7.
    // LDS dest linear; global slot pre-XOR'd by (srow&7) (involution).
    const int srow = tid >> 3;
    const bf16_t* gA = A + (size_t)(brow + srow) * K + (((tid & 7) ^ (srow & 7)) << 3);
    bf16_t* lA = &sA[(srow << 6) + ((tid & 7) << 3)];

    const int KS = K >> 5;
    const bf16_t* gBf = Bp + (size_t)((bcol >> 4) + wn * 4) * KS * 512 + lane * 8;

    const int l15 = lane & 15, sq = lane >> 4, sx = lane & 7;
    const int arow0 = wm * 64 + l15;
    const int NT = K >> 6;                           // 16 (FFN1) / 64 (FFN2), even

    f32x4 acc[4][4];
#pragma unroll
    for (int i = 0; i < 4; ++i)
#pragma unroll
        for (int j = 0; j < 4; ++j) acc[i][j] = (f32x4){0.f, 0.f, 0.f, 0.f};

    bf16x8 af[4][2];
    bf16x8 x0, x1, x2, x3, x4, x5, x6, x7;
    bf16x8 y0, y1, y2, y3, y4, y5, y6, y7;

#define G_SB   __builtin_amdgcn_sched_barrier(0)
#define G_BAR  { G_SB; __builtin_amdgcn_s_barrier(); G_SB; }
#define G_LG0  { asm volatile("s_waitcnt lgkmcnt(0)" ::: "memory"); G_SB; }
#define G_VM8  { asm volatile("s_waitcnt vmcnt(8)" ::: "memory"); G_SB; }
#define G_STAGE(t) { \
    gll16(gA + (size_t)(t) * 64,                     lA); \
    gll16(gA + (size_t)32 * K + (size_t)(t) * 64,    lA + 2048); \
    gll16(gA + (size_t)64 * K + (size_t)(t) * 64,    lA + 4096); \
    gll16(gA + (size_t)96 * K + (size_t)(t) * 64,    lA + 6144); \
    G_SB; }
#define G_LOADB(B0, B1, B2, B3, B4, B5, B6, B7, t) { \
    const bf16_t* _b = gBf + (size_t)2 * (t) * 512; \
    B0 = *(const bf16x8*)(_b); \
    B1 = *(const bf16x8*)(_b + 512); \
    B2 = *(const bf16x8*)(_b + (size_t)KS * 512); \
    B3 = *(const bf16x8*)(_b + (size_t)KS * 512 + 512); \
    B4 = *(const bf16x8*)(_b + (size_t)2 * KS * 512); \
    B5 = *(const bf16x8*)(_b + (size_t)2 * KS * 512 + 512); \
    B6 = *(const bf16x8*)(_b + (size_t)3 * KS * 512); \
    B7 = *(const bf16x8*)(_b + (size_t)3 * KS * 512 + 512); }
#define G_ADS() { \
    _Pragma("unroll") for (int m = 0; m < 4; ++m) { \
        af[m][0] = *(const bf16x8*)(&sA[(arow0 + m * 16) * 64 + ((sq ^ sx) << 3)]); \
        af[m][1] = *(const bf16x8*)(&sA[(arow0 + m * 16) * 64 + (((4 | sq) ^ sx) << 3)]); } }
#define G_MMA(B0, B1, B2, B3, B4, B5, B6, B7) { \
    __builtin_amdgcn_s_setprio(1); \
    _Pragma("unroll") for (int m = 0; m < 4; ++m) { \
        acc[m][0] = __builtin_amdgcn_mfma_f32_16x16x32_bf16(af[m][0], B0, acc[m][0], 0, 0, 0); \
        acc[m][1] = __builtin_amdgcn_mfma_f32_16x16x32_bf16(af[m][0], B2, acc[m][1], 0, 0, 0); \
        acc[m][2] = __builtin_amdgcn_mfma_f32_16x16x32_bf16(af[m][0], B4, acc[m][2], 0, 0, 0); \
        acc[m][3] = __builtin_amdgcn_mfma_f32_16x16x32_bf16(af[m][0], B6, acc[m][3], 0, 0, 0); } \
    _Pragma("unroll") for (int m = 0; m < 4; ++m) { \
        acc[m][0] = __builtin_amdgcn_mfma_f32_16x16x32_bf16(af[m][1], B1, acc[m][0], 0, 0, 0); \
        acc[m][1] = __builtin_amdgcn_mfma_f32_16x16x32_bf16(af[m][1], B3, acc[m][1], 0, 0, 0); \
        acc[m][2] = __builtin_amdgcn_mfma_f32_16x16x32_bf16(af[m][1], B5, acc[m][2], 0, 0, 0); \
        acc[m][3] = __builtin_amdgcn_mfma_f32_16x16x32_bf16(af[m][1], B7, acc[m][3], 0, 0, 0); } \
    __builtin_amdgcn_s_setprio(0); }
// One pipelined K-tile: read frags(t) -> publish-done barrier -> stage(t+1) ->
// load B(t+1) (stays in flight) -> MFMA(t) -> retire stage glls -> publish barrier.
#define G_ITER(t, C0,C1,C2,C3,C4,C5,C6,C7, N0,N1,N2,N3,N4,N5,N6,N7) { \
    G_ADS(); G_LG0; G_BAR; \
    G_STAGE((t) + 1); \
    G_LOADB(N0,N1,N2,N3,N4,N5,N6,N7, (t) + 1); \
    G_MMA(C0,C1,C2,C3,C4,C5,C6,C7); \
    G_VM8; G_BAR; }

    // prologue: tile 0 staged + B(0) in regs; exactly 8 outstanding vmem after G_VM8
    G_STAGE(0);
    G_LOADB(x0, x1, x2, x3, x4, x5, x6, x7, 0);
    G_VM8; G_BAR;

    // branch-free steady state (NT-2 even)
    for (int t = 0; t < NT - 2; t += 2) {
        G_ITER(t,     x0,x1,x2,x3,x4,x5,x6,x7, y0,y1,y2,y3,y4,y5,y6,y7);
        G_ITER(t + 1, y0,y1,y2,y3,y4,y5,y6,y7, x0,x1,x2,x3,x4,x5,x6,x7);
    }
    // peeled: compute NT-2 (stages+loads NT-1), then last tile (no staging)
    G_ITER(NT - 2, x0,x1,x2,x3,x4,x5,x6,x7, y0,y1,y2,y3,y4,y5,y6,y7);
    G_ADS(); G_LG0;
    G_MMA(y0, y1, y2, y3, y4, y5, y6, y7);

#undef G_ITER
#undef G_MMA
#undef G_ADS
#undef G_LOADB
#undef G_STAGE
#undef G_VM8
#undef G_LG0
#undef G_BAR
#undef G_SB

    // epilogue: C/D layout col=lane&15, row=(lane>>4)*4+reg
    const int r0 = brow + wm * 64 + (sq << 2);
    const int c0 = bcol + wn * 64 + l15;
#pragma unroll
    for (int m = 0; m < 4; ++m)
#pragma unroll
        for (int n = 0; n < 4; ++n) {
            const int col = c0 + n * 16;
#pragma unroll
            for (int r = 0; r < 4; ++r) {
                const int row = r0 + m * 16 + r;
                const float v = acc[m][n][r];
                if constexpr (EPI == 2) {
                    ob[(size_t)row * N + col] = (bf16_t)fmaxf(v + bias[col], 0.f);
                } else {
                    outf[(size_t)row * N + col] = res[(size_t)row * N + col] + v + bias[col];
                }
            }
        }
    (void)M;
}

// ---------------- split-KV flash attention partials ----------------
__global__ __launch_bounds__(256)
void attn_partial(const bf16_t* __restrict__ Q, const bf16_t* __restrict__ Kb,
                  const bf16_t* __restrict__ VT,
                  float* __restrict__ po, float* __restrict__ pml) {
    const int tid = threadIdx.x, lane = tid & 63, w = tid >> 6;
    const int j = blockIdx.x * 4 + w;           // job id, 0..4351

    int a = 0;
    while (j >= 16 * (a + 1) * (a + 2)) ++a;    // a in 0..15
    const int r_in = j - 16 * a * (a + 1);
    const int idx = r_in / (a + 1);             // 0..31
    const int chunk = r_in - idx * (a + 1);     // 0..a
    const int g = a * 8 + (idx >> 2);           // diag kv-tile 0..127
    const int qi = g * 4 + (idx & 3);           // q-subtile 0..511

    __shared__ __align__(16) bf16_t P[4][16 * 64];
    const int l15 = lane & 15, hi = lane >> 4;
    const int koff = hi * 8;
    const int qrow = qi * 16 + l15;
    const bf16x8 qf0 = *(const bf16x8*)(Q + qrow * 64 + koff);
    const bf16x8 qf1 = *(const bf16x8*)(Q + qrow * 64 + 32 + koff);

    float m_run[4], l_run[4];
    f32x4 oacc[4];
#pragma unroll
    for (int r = 0; r < 4; ++r) { m_run[r] = -1e30f; l_run[r] = 0.f; }
#pragma unroll
    for (int d = 0; d < 4; ++d) oacc[d] = (f32x4){0.f, 0.f, 0.f, 0.f};

    const int t0 = chunk * 8;
    const int t1 = min(t0 + 8, g + 1);
    for (int t = t0; t < t1; ++t) {
        const int kv0 = t << 6;
        f32x4 s[4];
#pragma unroll
        for (int ni = 0; ni < 4; ++ni) s[ni] = (f32x4){0.f, 0.f, 0.f, 0.f};
#pragma unroll
        for (int ni = 0; ni < 4; ++ni) {
            const bf16_t* kp = Kb + (kv0 + ni * 16 + l15) * 64 + koff;
            bf16x8 kf0 = *(const bf16x8*)(kp);
            bf16x8 kf1 = *(const bf16x8*)(kp + 32);
            s[ni] = __builtin_amdgcn_mfma_f32_16x16x32_bf16(qf0, kf0, s[ni], 0, 0, 0);
            s[ni] = __builtin_amdgcn_mfma_f32_16x16x32_bf16(qf1, kf1, s[ni], 0, 0, 0);
        }
        if (t == g) {
#pragma unroll
            for (int ni = 0; ni < 4; ++ni)
#pragma unroll
                for (int r = 0; r < 4; ++r) {
                    const int col = kv0 + ni * 16 + l15;
                    const int row = qi * 16 + hi * 4 + r;
                    if (col > row) s[ni][r] = -1e30f;
                }
        }
        float pv[4][4], alpha[4];
#pragma unroll
        for (int r = 0; r < 4; ++r) {
            float vm = fmaxf(fmaxf(s[0][r], s[1][r]), fmaxf(s[2][r], s[3][r]));
            vm = fmaxf(vm, __shfl_xor(vm, 1));
            vm = fmaxf(vm, __shfl_xor(vm, 2));
            vm = fmaxf(vm, __shfl_xor(vm, 4));
            vm = fmaxf(vm, __shfl_xor(vm, 8));
            const float mnew = fmaxf(m_run[r], vm);
            float sum = 0.f;
#pragma unroll
            for (int ni = 0; ni < 4; ++ni) {
                float p = __expf(s[ni][r] - mnew);
                pv[ni][r] = p; sum += p;
            }
            sum += __shfl_xor(sum, 1); sum += __shfl_xor(sum, 2);
            sum += __shfl_xor(sum, 4); sum += __shfl_xor(sum, 8);
            alpha[r] = __expf(m_run[r] - mnew);
            l_run[r] = l_run[r] * alpha[r] + sum;
            m_run[r] = mnew;
        }
#pragma unroll
        for (int d = 0; d < 4; ++d)
#pragma unroll
            for (int r = 0; r < 4; ++r) oacc[d][r] *= alpha[r];
        asm volatile("s_waitcnt lgkmcnt(0)" ::: "memory");
        __builtin_amdgcn_sched_barrier(0);
#pragma unroll
        for (int ni = 0; ni < 4; ++ni)
#pragma unroll
            for (int r = 0; r < 4; ++r)
                P[w][(hi * 4 + r) * 64 + ni * 16 + l15] = (bf16_t)pv[ni][r];
        asm volatile("s_waitcnt lgkmcnt(0)" ::: "memory");
        __builtin_amdgcn_sched_barrier(0);
#pragma unroll
        for (int ks = 0; ks < 2; ++ks) {
            bf16x8 pf = *(const bf16x8*)(&P[w][l15 * 64 + ks * 32 + koff]);
#pragma unroll
            for (int d = 0; d < 4; ++d) {
                bf16x8 vf = *(const bf16x8*)(VT + (size_t)(d * 16 + l15) * T_SEQ + kv0 + ks * 32 + koff);
                oacc[d] = __builtin_amdgcn_mfma_f32_16x16x32_bf16(pf, vf, oacc[d], 0, 0, 0);
            }
        }
    }
#pragma unroll
    for (int d = 0; d < 4; ++d)
#pragma unroll
        for (int r = 0; r < 4; ++r)
            po[(size_t)j * 1024 + (hi * 4 + r) * 64 + d * 16 + l15] = oacc[d][r];
    if (l15 == 0) {
#pragma unroll
        for (int r = 0; r < 4; ++r) {
            pml[(size_t)j * 32 + hi * 4 + r] = m_run[r];
            pml[(size_t)j * 32 + 16 + hi * 4 + r] = l_run[r];
        }
    }
}

// ---------------- combine partials: 256 thr/block, thread=(row, 4 cols), ILP over i ----
__global__ __launch_bounds__(256)
void attn_reduce(const float* __restrict__ po, const float* __restrict__ pml,
                 bf16_t* __restrict__ O) {
    const int qi = blockIdx.x;        // 0..511
    const int tid = threadIdx.x;
    const int row = tid >> 4;         // 0..15
    const int cg = tid & 15;          // 4 cols each
    const int g = qi >> 2;
    const int a = g >> 3;
    const int idx = ((g & 7) << 2) | (qi & 3);
    const int base = 16 * a * (a + 1) + idx * (a + 1);
    const int cnt = a + 1;

    float M = -1e30f;
    for (int i = 0; i < cnt; ++i)
        M = fmaxf(M, pml[(size_t)(base + i) * 32 + row]);
    float L = 0.f;
    f32x4 o = (f32x4){0.f, 0.f, 0.f, 0.f};
    for (int i = 0; i < cnt; ++i) {
        const float m = pml[(size_t)(base + i) * 32 + row];
        const float l = pml[(size_t)(base + i) * 32 + 16 + row];
        const float wgt = __expf(m - M);
        L += l * wgt;
        const f32x4 v = *(const f32x4*)&po[(size_t)(base + i) * 1024 + row * 64 + cg * 4];
#pragma unroll
        for (int u = 0; u < 4; ++u) o[u] += v[u] * wgt;
    }
    const float inv = 1.f / L;
    bf16x4 h;
#pragma unroll
    for (int u = 0; u < 4; ++u) h[u] = (bf16_t)(o[u] * inv);
    *(bf16x4*)(O + (size_t)(qi * 16 + row) * 64 + cg * 4) = h;
}

// ---------------- row LayerNorm (1024 cols), optional bf16 twin output ----------------
__global__ __launch_bounds__(256)
void ln_fused(const float* __restrict__ in, const float* __restrict__ g,
              const float* __restrict__ b, float* __restrict__ o32,
              bf16_t* __restrict__ o16) {
    const int row = blockIdx.x, tid = threadIdx.x;
    const float4 v = ((const float4*)(in + (size_t)row * NE))[tid];
    float s = v.x + v.y + v.z + v.w;
    float ss = v.x * v.x + v.y * v.y + v.z * v.z + v.w * v.w;
#pragma unroll
    for (int off = 1; off < 64; off <<= 1) {
        s  += __shfl_xor(s, off);
        ss += __shfl_xor(ss, off);
    }
    __shared__ float red[8];
    const int wv = tid >> 6, lane = tid & 63;
    if (lane == 0) { red[wv] = s; red[4 + wv] = ss; }
    __syncthreads();
    s  = red[0] + red[1] + red[2] + red[3];
    ss = red[4] + red[5] + red[6] + red[7];
    const float mu = s * (1.f / NE);
    const float rstd = rsqrtf(ss * (1.f / NE) - mu * mu + 1e-5f);
    const float4 gg = ((const float4*)g)[tid];
    const float4 bb = ((const float4*)b)[tid];
    float4 o;
    o.x = (v.x - mu) * rstd * gg.x + bb.x;
    o.y = (v.y - mu) * rstd * gg.y + bb.y;
    o.z = (v.z - mu) * rstd * gg.z + bb.z;
    o.w = (v.w - mu) * rstd * gg.w + bb.w;
    if (o32) ((float4*)(o32 + (size_t)row * NE))[tid] = o;
    if (o16) {
        bf16x4 h;
        h[0] = (bf16_t)o.x; h[1] = (bf16_t)o.y; h[2] = (bf16_t)o.z; h[3] = (bf16_t)o.w;
        *(bf16x4*)(o16 + (size_t)row * NE + tid * 4) = h;
    }
}

extern "C" void kernel_launch(void* const* d_in, const int* in_sizes, int n_in,
                              void* d_out, int out_size, void* d_ws, size_t ws_size,
                              hipStream_t stream) {
    (void)in_sizes; (void)n_in; (void)out_size; (void)ws_size;
    const float* x   = (const float*)d_in[0];
    const float* Wk  = (const float*)d_in[1];
    const float* Wq  = (const float*)d_in[2];
    const float* Wv  = (const float*)d_in[3];
    const float* Wp  = (const float*)d_in[4];
    const float* W1  = (const float*)d_in[5];
    const float* b1  = (const float*)d_in[6];
    const float* W2  = (const float*)d_in[7];
    const float* b2  = (const float*)d_in[8];
    const float* g1  = (const float*)d_in[9];
    const float* be1 = (const float*)d_in[10];
    const float* g2  = (const float*)d_in[11];
    const float* be2 = (const float*)d_in[12];
    float* out = (float*)d_out;

    char* ws = (char*)d_ws;
    bf16_t* xb   = (bf16_t*)(ws);                    // 16 MiB  x bf16
    bf16_t* x1b  = (bf16_t*)(ws + 16777216);         // 16 MiB  x1 bf16
    bf16_t* hb   = (bf16_t*)(ws + 33554432);         // 64 MiB  hidden bf16 (FFN phase)
    float*  po   = (float*)(ws + 33554432);          // 17.8 MiB attn partials (overlaps hb)
    float*  pml  = (float*)(ws + 33554432 + 18874368); // 0.6 MiB m/l partials
    bf16_t* W1p  = (bf16_t*)(ws + 100663296);        // 8 MiB  W1 packed B-frags
    bf16_t* W2p  = (bf16_t*)(ws + 109051904);        // 8 MiB  W2 packed B-frags
    bf16_t* Wkqv = (bf16_t*)(ws + 117440512);        // 512 KiB (256x1024)
    bf16_t* WpT  = (bf16_t*)(ws + 117964800);        // 128 KiB
    bf16_t* kb   = (bf16_t*)(ws + 118095872);        // 1 MiB
    bf16_t* qb   = (bf16_t*)(ws + 119144448);        // 1 MiB
    bf16_t* vT   = (bf16_t*)(ws + 120193024);        // 1 MiB (64 x 8192)
    bf16_t* a0   = (bf16_t*)(ws + 121241600);        // 1 MiB attn out
    float*  r1   = (float*)(ws + 122290176);         // 32 MiB residual1 / x1
    float*  r2   = (float*)(ws + 155844608);         // 32 MiB residual2

    cast_f32_bf16<<<8192, 256, 0, stream>>>(x, xb, 2097152);
    build_wkqv<<<1024, 256, 0, stream>>>(Wk, Wq, Wv, Wkqv);
    tcast<<<dim3(16, 1), 256, 0, stream>>>(Wp, WpT, 64, 1024);
    pack_bfrag<<<2048, 256, 0, stream>>>(W1, W1p, 4096, 32);    // NF=256, KS=32
    pack_bfrag<<<2048, 256, 0, stream>>>(W2, W2p, 1024, 128);   // NF=64,  KS=128

    // k,q,v projections (N padded to 256)
    gemm_bt<0><<<64 * 2, 256, 0, stream>>>(xb, Wkqv, 8192, 256, 1024,
                                           nullptr, kb, qb, vT, nullptr, nullptr);
    // causal flash attention: split-KV partials + reduce
    attn_partial<<<1088, 256, 0, stream>>>(qb, kb, vT, po, pml);
    attn_reduce<<<512, 256, 0, stream>>>(po, pml, a0);
    // proj + residual: r1 = x + a0 @ Wp
    gemm_bt<1><<<64 * 8, 256, 0, stream>>>(a0, WpT, 8192, 1024, 64,
                                           r1, nullptr, nullptr, nullptr, x, nullptr);
    // x1 = LN(r1)  (in-place fp32) + bf16 twin
    ln_fused<<<8192, 256, 0, stream>>>(r1, g1, be1, r1, x1b);
    // h = relu(x1 @ W1 + b1)   [B-global GEMM v2]
    gemm_bg<2><<<2048, 256, 0, stream>>>(x1b, W1p, 8192, 4096, 1024,
                                         nullptr, hb, nullptr, b1);
    // r2 = x1 + h @ W2 + b2    [B-global GEMM v2]
    gemm_bg<3><<<512, 256, 0, stream>>>(hb, W2p, 8192, 1024, 4096,
                                        r2, nullptr, r1, b2);
    // out = LN(r2)
    ln_fused<<<8192, 256, 0, stream>>>(r2, g2, be2, out, nullptr);
}

// Round 6
// 355.260 us; speedup vs baseline: 1.7414x; 1.0084x over previous
//
#include <hip/hip_runtime.h>
#include <hip/hip_bf16.h>

#define T_SEQ 8192
#define NE 1024
#define FF 4096

typedef __bf16 bf16_t;
typedef __bf16 bf16x8 __attribute__((ext_vector_type(8)));
typedef __bf16 bf16x4 __attribute__((ext_vector_type(4)));
typedef float f32x4 __attribute__((ext_vector_type(4)));

__device__ __forceinline__ void gll16(const void* g, void* l) {
    __builtin_amdgcn_global_load_lds(
        (const __attribute__((address_space(1))) void*)g,
        (__attribute__((address_space(3))) void*)l, 16, 0, 0);
}

// ---------------- elementwise cast fp32 -> bf16 (x4 per thread) ----------------
__global__ __launch_bounds__(256) void cast_f32_bf16(const float* __restrict__ in,
                                                     bf16_t* __restrict__ out, int n4) {
    int i = blockIdx.x * 256 + threadIdx.x;
    if (i >= n4) return;
    float4 v = ((const float4*)in)[i];
    bf16x4 h;
    h[0] = (bf16_t)v.x; h[1] = (bf16_t)v.y; h[2] = (bf16_t)v.z; h[3] = (bf16_t)v.w;
    ((bf16x4*)out)[i] = h;
}

// ---------------- build packed [Wk | Wq*0.125 | Wv | 0pad] as (256 x 1024) bf16, N-major ----------------
__global__ __launch_bounds__(256) void build_wkqv(const float* __restrict__ Wk,
                                                  const float* __restrict__ Wq,
                                                  const float* __restrict__ Wv,
                                                  bf16_t* __restrict__ out) {
    int idx = blockIdx.x * 256 + threadIdx.x;   // over 256*1024
    int n  = idx >> 10;   // 0..255  (output head-col)
    int kk = idx & 1023;  // 0..1023 (embd)
    float v = 0.f;
    if (n < 64)       v = Wk[kk * 64 + n];
    else if (n < 128) v = Wq[kk * 64 + (n - 64)] * 0.125f;  // fold 1/sqrt(hs)
    else if (n < 192) v = Wv[kk * 64 + (n - 128)];
    out[idx] = (bf16_t)v;
}

// ---------------- tiled transpose + cast: in (R x C) f32 -> out (C x R) bf16 ----------------
__global__ __launch_bounds__(256) void tcast(const float* __restrict__ in,
                                             bf16_t* __restrict__ out, int R, int C) {
    __shared__ bf16_t tl[64][66];
    const int bc = blockIdx.x << 6, br = blockIdx.y << 6;
    const int tx = threadIdx.x & 63, ty = threadIdx.x >> 6;
#pragma unroll
    for (int j = 0; j < 16; ++j) {
        const int r = ty + j * 4;
        tl[r][tx] = (bf16_t)in[(size_t)(br + r) * C + bc + tx];
    }
    __syncthreads();
#pragma unroll
    for (int j = 0; j < 16; ++j) {
        const int r = ty + j * 4;
        out[(size_t)(bc + r) * R + br + tx] = tl[tx][r];
    }
}

// ---------------- legacy 128x128 GEMM (kept for QKV + proj epilogues) ----------
template <int EPI>
__global__ __launch_bounds__(256, 2)
void gemm_bt(const bf16_t* __restrict__ A, const bf16_t* __restrict__ Bt,
             int M, int N, int K,
             float* __restrict__ outf,
             bf16_t* __restrict__ ob0, bf16_t* __restrict__ ob1, bf16_t* __restrict__ ob2,
             const float* __restrict__ res, const float* __restrict__ bias) {
    const int tid  = threadIdx.x;
    const int lane = tid & 63;
    const int tiles_n = N >> 7;
    const int tm = blockIdx.x / tiles_n;
    const int tn = blockIdx.x % tiles_n;
    const int brow = tm << 7, bcol = tn << 7;

    __shared__ __align__(16) bf16_t As[128 * 32];
    __shared__ __align__(16) bf16_t Bs[128 * 32];

    const int c1 = tid, c2 = tid + 256;
    const int s1 = (((c1 & 3) ^ ((c1 >> 3) & 3)) * 8);
    const int s2 = (((c2 & 3) ^ ((c2 >> 3) & 3)) * 8);
    const bf16_t* gA1 = A + (size_t)(brow + (c1 >> 2)) * K + s1;
    const bf16_t* gA2 = A + (size_t)(brow + (c2 >> 2)) * K + s2;
    const bf16_t* gB1 = Bt + (size_t)(bcol + (c1 >> 2)) * K + s1;
    const bf16_t* gB2 = Bt + (size_t)(bcol + (c2 >> 2)) * K + s2;
    bf16_t* lA1 = As + c1 * 8; bf16_t* lA2 = As + c2 * 8;
    bf16_t* lB1 = Bs + c1 * 8; bf16_t* lB2 = Bs + c2 * 8;

    const int wv = tid >> 6;
    const int wr = (wv >> 1) * 64, wc = (wv & 1) * 64;
    const int arow  = wr + (lane & 15);
    const int brf   = wc + (lane & 15);
    const int koff = (((lane >> 4) ^ ((lane >> 1) & 3)) * 8);

    f32x4 acc[4][4];
#pragma unroll
    for (int i = 0; i < 4; ++i)
#pragma unroll
        for (int j = 0; j < 4; ++j) acc[i][j] = (f32x4){0.f, 0.f, 0.f, 0.f};

    for (int k0 = 0; k0 < K; k0 += 32) {
        gll16(gA1, lA1); gll16(gA2, lA2);
        gll16(gB1, lB1); gll16(gB2, lB2);
        gA1 += 32; gA2 += 32; gB1 += 32; gB2 += 32;
        __syncthreads();
        bf16x8 af[4], bfr[4];
#pragma unroll
        for (int mi = 0; mi < 4; ++mi)
            af[mi] = *(const bf16x8*)(As + (arow + mi * 16) * 32 + koff);
#pragma unroll
        for (int ni = 0; ni < 4; ++ni)
            bfr[ni] = *(const bf16x8*)(Bs + (brf + ni * 16) * 32 + koff);
#pragma unroll
        for (int mi = 0; mi < 4; ++mi)
#pragma unroll
            for (int ni = 0; ni < 4; ++ni)
                acc[mi][ni] = __builtin_amdgcn_mfma_f32_16x16x32_bf16(
                    af[mi], bfr[ni], acc[mi][ni], 0, 0, 0);
        __syncthreads();
    }

    const int r0 = brow + wr + ((lane >> 4) << 2);
    const int c0 = bcol + wc + (lane & 15);
#pragma unroll
    for (int mi = 0; mi < 4; ++mi)
#pragma unroll
        for (int ni = 0; ni < 4; ++ni)
#pragma unroll
            for (int r = 0; r < 4; ++r) {
                const int row = r0 + mi * 16 + r;
                const int col = c0 + ni * 16;
                const float v = acc[mi][ni][r];
                if constexpr (EPI == 0) {
                    if (col < 64)       ob0[row * 64 + col] = (bf16_t)v;             // k
                    else if (col < 128) ob1[row * 64 + (col - 64)] = (bf16_t)v;      // q (pre-scaled)
                    else if (col < 192) ob2[(size_t)(col - 128) * T_SEQ + row] = (bf16_t)v; // v^T
                } else if constexpr (EPI == 1) {
                    outf[(size_t)row * N + col] = res[(size_t)row * N + col] + v;
                } else if constexpr (EPI == 2) {
                    ob0[(size_t)row * N + col] = (bf16_t)fmaxf(v + bias[col], 0.f);
                } else {
                    outf[(size_t)row * N + col] = res[(size_t)row * N + col] + v + bias[col];
                }
            }
}

// ---------------- 256x256 LDS-staged GEMM, BK=32 subtiles, depth-2 pipeline ----------
// C(MxN) = A(M x K @ stride lda) @ Bt(N x K @ stride ldb)^T, K per block (split via
// blockIdx.y: element offset y*K into the k dimension). 8 waves (2wm x 4wn), per-wave
// 128x64. LDS: 4 subtile buffers x (A 16KB + B 16KB) = 128 KB, layout [kslot4][row256][8elem]
// (gll dest wave-linear; ds_read quarter-wave hits 2-way bank alias = free).
// Pipeline: stage(t+2) while computing t; vmcnt(4) retires stage(t+1) before barrier.
// EPI 2: ob = bf16(relu(C + bias)); EPI 4: po{y}[row*N+col] = C (f32 partial).
template <int EPI>
__global__ __launch_bounds__(512, 1)
void gemm_ls(const bf16_t* __restrict__ A, int lda,
             const bf16_t* __restrict__ Bt, int ldb,
             int N, int K,
             bf16_t* __restrict__ ob, const float* __restrict__ bias,
             float* __restrict__ po0, float* __restrict__ po1) {
    __shared__ __align__(16) bf16_t sA[4][8192];
    __shared__ __align__(16) bf16_t sB[4][8192];
    const int tid = threadIdx.x, lane = tid & 63, w = tid >> 6;
    const int wm = w >> 2, wn = w & 3;

    const int nwg = gridDim.x;                       // %8 == 0 (512 / 128)
    const int wgid = (blockIdx.x & 7) * (nwg >> 3) + (blockIdx.x >> 3);
    const int tiles_n = N >> 8;
    const int tm = wgid / tiles_n, tn = wgid % tiles_n;
    const int brow = tm << 8, bcol = tn << 8;
    const size_t kofs = (size_t)blockIdx.y * K;      // split-K element offset

    // staging: wave w owns chunks {w*2, w*2+1} of A and of B (16 chunks each of
    // 64 rows x 8 k-elems): slot s0=(w&1)*2 (+1), row-block rbb=w>>1.
    const int s0 = (w & 1) * 2, rbb = w >> 1;
    const bf16_t* gA0 = A + (size_t)(brow + rbb * 64 + lane) * lda + kofs + s0 * 8;
    const bf16_t* gB0 = Bt + (size_t)(bcol + rbb * 64 + lane) * ldb + kofs + s0 * 8;
    const int dA0 = s0 * 2048 + (rbb * 64 + lane) * 8;   // elems; +2048 for slot s0+1

    const int l15 = lane & 15, sq = lane >> 4;
    const int aoff = sq * 2048 + (wm * 128 + l15) * 8;   // + m*128
    const int boff = sq * 2048 + (wn * 64 + l15) * 8;    // + n*128
    const int NTS = K >> 5;                              // 32 (FFN1) / 64 (FFN2 half)

    f32x4 acc[8][4];
#pragma unroll
    for (int i = 0; i < 8; ++i)
#pragma unroll
        for (int j = 0; j < 4; ++j) acc[i][j] = (f32x4){0.f, 0.f, 0.f, 0.f};
    bf16x8 af[8], bfr[4];

#define L_SB  __builtin_amdgcn_sched_barrier(0)
#define L_BAR { L_SB; __builtin_amdgcn_s_barrier(); L_SB; }
#define L_LG0 { asm volatile("s_waitcnt lgkmcnt(0)" ::: "memory"); L_SB; }
#define L_VM4 { asm volatile("s_waitcnt vmcnt(4)" ::: "memory"); L_SB; }
#define L_VM0 { asm volatile("s_waitcnt vmcnt(0)" ::: "memory"); L_SB; }
#define L_STAGE(t) { const int q_ = (t) & 3; \
    gll16(gA0 + (size_t)(t) * 32,        &sA[q_][dA0]); \
    gll16(gA0 + (size_t)(t) * 32 + 8,    &sA[q_][dA0 + 2048]); \
    gll16(gB0 + (size_t)(t) * 32,        &sB[q_][dA0]); \
    gll16(gB0 + (size_t)(t) * 32 + 8,    &sB[q_][dA0 + 2048]); \
    L_SB; }
#define L_DS(t) { const int q_ = (t) & 3; \
    _Pragma("unroll") for (int m = 0; m < 8; ++m) \
        af[m] = *(const bf16x8*)(&sA[q_][aoff + m * 128]); \
    _Pragma("unroll") for (int n = 0; n < 4; ++n) \
        bfr[n] = *(const bf16x8*)(&sB[q_][boff + n * 128]); }
#define L_MMA() { __builtin_amdgcn_s_setprio(1); \
    _Pragma("unroll") for (int m = 0; m < 8; ++m) \
    _Pragma("unroll") for (int n = 0; n < 4; ++n) \
        acc[m][n] = __builtin_amdgcn_mfma_f32_16x16x32_bf16(af[m], bfr[n], acc[m][n], 0, 0, 0); \
    __builtin_amdgcn_s_setprio(0); }

    // prologue: subtiles 0,1 in flight; wait subtile 0 resident
    L_STAGE(0); L_STAGE(1);
    L_VM4; L_BAR;
    // steady state: compute t, stage t+2, retire t+1 before publishing
    for (int t = 0; t < NTS - 2; ++t) {
        L_DS(t);
        L_STAGE(t + 2);
        L_LG0;
        L_MMA();
        L_VM4; L_BAR;
    }
    // tail: t = NTS-2 (drain stage(NTS-1)), then t = NTS-1
    L_DS(NTS - 2); L_LG0; L_MMA(); L_VM0; L_BAR;
    L_DS(NTS - 1); L_LG0; L_MMA();

#undef L_MMA
#undef L_DS
#undef L_STAGE
#undef L_VM0
#undef L_VM4
#undef L_LG0
#undef L_BAR
#undef L_SB

    // epilogue: C/D layout col=lane&15, row=(lane>>4)*4+reg
    const int r0 = brow + wm * 128 + sq * 4;
    const int c0 = bcol + wn * 64 + l15;
    float* po = blockIdx.y ? po1 : po0;
#pragma unroll
    for (int m = 0; m < 8; ++m)
#pragma unroll
        for (int n = 0; n < 4; ++n) {
            const int col = c0 + n * 16;
#pragma unroll
            for (int r = 0; r < 4; ++r) {
                const int row = r0 + m * 16 + r;
                const float v = acc[m][n][r];
                if constexpr (EPI == 2) {
                    ob[(size_t)row * N + col] = (bf16_t)fmaxf(v + bias[col], 0.f);
                } else {
                    po[(size_t)row * N + col] = v;
                }
            }
        }
}

// ---------------- split-KV flash attention partials ----------------
__global__ __launch_bounds__(256)
void attn_partial(const bf16_t* __restrict__ Q, const bf16_t* __restrict__ Kb,
                  const bf16_t* __restrict__ VT,
                  float* __restrict__ po, float* __restrict__ pml) {
    const int tid = threadIdx.x, lane = tid & 63, w = tid >> 6;
    const int j = blockIdx.x * 4 + w;           // job id, 0..4351

    int a = 0;
    while (j >= 16 * (a + 1) * (a + 2)) ++a;    // a in 0..15
    const int r_in = j - 16 * a * (a + 1);
    const int idx = r_in / (a + 1);             // 0..31
    const int chunk = r_in - idx * (a + 1);     // 0..a
    const int g = a * 8 + (idx >> 2);           // diag kv-tile 0..127
    const int qi = g * 4 + (idx & 3);           // q-subtile 0..511

    __shared__ __align__(16) bf16_t P[4][16 * 64];
    const int l15 = lane & 15, hi = lane >> 4;
    const int koff = hi * 8;
    const int qrow = qi * 16 + l15;
    const bf16x8 qf0 = *(const bf16x8*)(Q + qrow * 64 + koff);
    const bf16x8 qf1 = *(const bf16x8*)(Q + qrow * 64 + 32 + koff);

    float m_run[4], l_run[4];
    f32x4 oacc[4];
#pragma unroll
    for (int r = 0; r < 4; ++r) { m_run[r] = -1e30f; l_run[r] = 0.f; }
#pragma unroll
    for (int d = 0; d < 4; ++d) oacc[d] = (f32x4){0.f, 0.f, 0.f, 0.f};

    const int t0 = chunk * 8;
    const int t1 = min(t0 + 8, g + 1);
    for (int t = t0; t < t1; ++t) {
        const int kv0 = t << 6;
        f32x4 s[4];
#pragma unroll
        for (int ni = 0; ni < 4; ++ni) s[ni] = (f32x4){0.f, 0.f, 0.f, 0.f};
#pragma unroll
        for (int ni = 0; ni < 4; ++ni) {
            const bf16_t* kp = Kb + (kv0 + ni * 16 + l15) * 64 + koff;
            bf16x8 kf0 = *(const bf16x8*)(kp);
            bf16x8 kf1 = *(const bf16x8*)(kp + 32);
            s[ni] = __builtin_amdgcn_mfma_f32_16x16x32_bf16(qf0, kf0, s[ni], 0, 0, 0);
            s[ni] = __builtin_amdgcn_mfma_f32_16x16x32_bf16(qf1, kf1, s[ni], 0, 0, 0);
        }
        if (t == g) {
#pragma unroll
            for (int ni = 0; ni < 4; ++ni)
#pragma unroll
                for (int r = 0; r < 4; ++r) {
                    const int col = kv0 + ni * 16 + l15;
                    const int row = qi * 16 + hi * 4 + r;
                    if (col > row) s[ni][r] = -1e30f;
                }
        }
        float pv[4][4], alpha[4];
#pragma unroll
        for (int r = 0; r < 4; ++r) {
            float vm = fmaxf(fmaxf(s[0][r], s[1][r]), fmaxf(s[2][r], s[3][r]));
            vm = fmaxf(vm, __shfl_xor(vm, 1));
            vm = fmaxf(vm, __shfl_xor(vm, 2));
            vm = fmaxf(vm, __shfl_xor(vm, 4));
            vm = fmaxf(vm, __shfl_xor(vm, 8));
            const float mnew = fmaxf(m_run[r], vm);
            float sum = 0.f;
#pragma unroll
            for (int ni = 0; ni < 4; ++ni) {
                float p = __expf(s[ni][r] - mnew);
                pv[ni][r] = p; sum += p;
            }
            sum += __shfl_xor(sum, 1); sum += __shfl_xor(sum, 2);
            sum += __shfl_xor(sum, 4); sum += __shfl_xor(sum, 8);
            alpha[r] = __expf(m_run[r] - mnew);
            l_run[r] = l_run[r] * alpha[r] + sum;
            m_run[r] = mnew;
        }
#pragma unroll
        for (int d = 0; d < 4; ++d)
#pragma unroll
            for (int r = 0; r < 4; ++r) oacc[d][r] *= alpha[r];
        asm volatile("s_waitcnt lgkmcnt(0)" ::: "memory");
        __builtin_amdgcn_sched_barrier(0);
#pragma unroll
        for (int ni = 0; ni < 4; ++ni)
#pragma unroll
            for (int r = 0; r < 4; ++r)
                P[w][(hi * 4 + r) * 64 + ni * 16 + l15] = (bf16_t)pv[ni][r];
        asm volatile("s_waitcnt lgkmcnt(0)" ::: "memory");
        __builtin_amdgcn_sched_barrier(0);
#pragma unroll
        for (int ks = 0; ks < 2; ++ks) {
            bf16x8 pf = *(const bf16x8*)(&P[w][l15 * 64 + ks * 32 + koff]);
#pragma unroll
            for (int d = 0; d < 4; ++d) {
                bf16x8 vf = *(const bf16x8*)(VT + (size_t)(d * 16 + l15) * T_SEQ + kv0 + ks * 32 + koff);
                oacc[d] = __builtin_amdgcn_mfma_f32_16x16x32_bf16(pf, vf, oacc[d], 0, 0, 0);
            }
        }
    }
#pragma unroll
    for (int d = 0; d < 4; ++d)
#pragma unroll
        for (int r = 0; r < 4; ++r)
            po[(size_t)j * 1024 + (hi * 4 + r) * 64 + d * 16 + l15] = oacc[d][r];
    if (l15 == 0) {
#pragma unroll
        for (int r = 0; r < 4; ++r) {
            pml[(size_t)j * 32 + hi * 4 + r] = m_run[r];
            pml[(size_t)j * 32 + 16 + hi * 4 + r] = l_run[r];
        }
    }
}

// ---------------- combine partials: 256 thr/block, thread=(row, 4 cols), ILP over i ----
__global__ __launch_bounds__(256)
void attn_reduce(const float* __restrict__ po, const float* __restrict__ pml,
                 bf16_t* __restrict__ O) {
    const int qi = blockIdx.x;        // 0..511
    const int tid = threadIdx.x;
    const int row = tid >> 4;         // 0..15
    const int cg = tid & 15;          // 4 cols each
    const int g = qi >> 2;
    const int a = g >> 3;
    const int idx = ((g & 7) << 2) | (qi & 3);
    const int base = 16 * a * (a + 1) + idx * (a + 1);
    const int cnt = a + 1;

    float M = -1e30f;
    for (int i = 0; i < cnt; ++i)
        M = fmaxf(M, pml[(size_t)(base + i) * 32 + row]);
    float L = 0.f;
    f32x4 o = (f32x4){0.f, 0.f, 0.f, 0.f};
    for (int i = 0; i < cnt; ++i) {
        const float m = pml[(size_t)(base + i) * 32 + row];
        const float l = pml[(size_t)(base + i) * 32 + 16 + row];
        const float wgt = __expf(m - M);
        L += l * wgt;
        const f32x4 v = *(const f32x4*)&po[(size_t)(base + i) * 1024 + row * 64 + cg * 4];
#pragma unroll
        for (int u = 0; u < 4; ++u) o[u] += v[u] * wgt;
    }
    const float inv = 1.f / L;
    bf16x4 h;
#pragma unroll
    for (int u = 0; u < 4; ++u) h[u] = (bf16_t)(o[u] * inv);
    *(bf16x4*)(O + (size_t)(qi * 16 + row) * 64 + cg * 4) = h;
}

// ---------------- row LayerNorm (1024 cols), optional bf16 twin output ----------------
__global__ __launch_bounds__(256)
void ln_fused(const float* __restrict__ in, const float* __restrict__ g,
              const float* __restrict__ b, float* __restrict__ o32,
              bf16_t* __restrict__ o16) {
    const int row = blockIdx.x, tid = threadIdx.x;
    const float4 v = ((const float4*)(in + (size_t)row * NE))[tid];
    float s = v.x + v.y + v.z + v.w;
    float ss = v.x * v.x + v.y * v.y + v.z * v.z + v.w * v.w;
#pragma unroll
    for (int off = 1; off < 64; off <<= 1) {
        s  += __shfl_xor(s, off);
        ss += __shfl_xor(ss, off);
    }
    __shared__ float red[8];
    const int wv = tid >> 6, lane = tid & 63;
    if (lane == 0) { red[wv] = s; red[4 + wv] = ss; }
    __syncthreads();
    s  = red[0] + red[1] + red[2] + red[3];
    ss = red[4] + red[5] + red[6] + red[7];
    const float mu = s * (1.f / NE);
    const float rstd = rsqrtf(ss * (1.f / NE) - mu * mu + 1e-5f);
    const float4 gg = ((const float4*)g)[tid];
    const float4 bb = ((const float4*)b)[tid];
    float4 o;
    o.x = (v.x - mu) * rstd * gg.x + bb.x;
    o.y = (v.y - mu) * rstd * gg.y + bb.y;
    o.z = (v.z - mu) * rstd * gg.z + bb.z;
    o.w = (v.w - mu) * rstd * gg.w + bb.w;
    if (o32) ((float4*)(o32 + (size_t)row * NE))[tid] = o;
    if (o16) {
        bf16x4 h;
        h[0] = (bf16_t)o.x; h[1] = (bf16_t)o.y; h[2] = (bf16_t)o.z; h[3] = (bf16_t)o.w;
        *(bf16x4*)(o16 + (size_t)row * NE + tid * 4) = h;
    }
}

// ---------------- final LN fused with split-K combine: LN(r1 + p0 + p1 + bias) ------
__global__ __launch_bounds__(256)
void ln_sum(const float* __restrict__ r1, const float* __restrict__ p0,
            const float* __restrict__ p1, const float* __restrict__ bias,
            const float* __restrict__ g, const float* __restrict__ b,
            float* __restrict__ out) {
    const int row = blockIdx.x, tid = threadIdx.x;
    const size_t off = (size_t)row * NE;
    const float4 a = ((const float4*)(r1 + off))[tid];
    const float4 q0 = ((const float4*)(p0 + off))[tid];
    const float4 q1 = ((const float4*)(p1 + off))[tid];
    const float4 bb4 = ((const float4*)bias)[tid];
    float4 v;
    v.x = a.x + q0.x + q1.x + bb4.x;
    v.y = a.y + q0.y + q1.y + bb4.y;
    v.z = a.z + q0.z + q1.z + bb4.z;
    v.w = a.w + q0.w + q1.w + bb4.w;
    float s = v.x + v.y + v.z + v.w;
    float ss = v.x * v.x + v.y * v.y + v.z * v.z + v.w * v.w;
#pragma unroll
    for (int off2 = 1; off2 < 64; off2 <<= 1) {
        s  += __shfl_xor(s, off2);
        ss += __shfl_xor(ss, off2);
    }
    __shared__ float red[8];
    const int wv = tid >> 6, lane = tid & 63;
    if (lane == 0) { red[wv] = s; red[4 + wv] = ss; }
    __syncthreads();
    s  = red[0] + red[1] + red[2] + red[3];
    ss = red[4] + red[5] + red[6] + red[7];
    const float mu = s * (1.f / NE);
    const float rstd = rsqrtf(ss * (1.f / NE) - mu * mu + 1e-5f);
    const float4 gg = ((const float4*)g)[tid];
    const float4 be = ((const float4*)b)[tid];
    float4 o;
    o.x = (v.x - mu) * rstd * gg.x + be.x;
    o.y = (v.y - mu) * rstd * gg.y + be.y;
    o.z = (v.z - mu) * rstd * gg.z + be.z;
    o.w = (v.w - mu) * rstd * gg.w + be.w;
    ((float4*)(out + off))[tid] = o;
}

extern "C" void kernel_launch(void* const* d_in, const int* in_sizes, int n_in,
                              void* d_out, int out_size, void* d_ws, size_t ws_size,
                              hipStream_t stream) {
    (void)in_sizes; (void)n_in; (void)out_size; (void)ws_size;
    const float* x   = (const float*)d_in[0];
    const float* Wk  = (const float*)d_in[1];
    const float* Wq  = (const float*)d_in[2];
    const float* Wv  = (const float*)d_in[3];
    const float* Wp  = (const float*)d_in[4];
    const float* W1  = (const float*)d_in[5];
    const float* b1  = (const float*)d_in[6];
    const float* W2  = (const float*)d_in[7];
    const float* b2  = (const float*)d_in[8];
    const float* g1  = (const float*)d_in[9];
    const float* be1 = (const float*)d_in[10];
    const float* g2  = (const float*)d_in[11];
    const float* be2 = (const float*)d_in[12];
    float* out = (float*)d_out;

    char* ws = (char*)d_ws;
    bf16_t* xb   = (bf16_t*)(ws);                    // 16 MiB  x bf16 (dead after QKV)
    bf16_t* x1b  = (bf16_t*)(ws + 16777216);         // 16 MiB  x1 bf16 (dead after FFN1)
    bf16_t* hb   = (bf16_t*)(ws + 33554432);         // 64 MiB  hidden bf16 (FFN phase)
    float*  po   = (float*)(ws + 33554432);          // 17.8 MiB attn partials (overlaps hb)
    float*  pml  = (float*)(ws + 33554432 + 18874368); // 0.6 MiB m/l partials
    bf16_t* W1t  = (bf16_t*)(ws + 100663296);        // 8 MiB  W1^T (4096x1024)
    bf16_t* W2t  = (bf16_t*)(ws + 109051904);        // 8 MiB  W2^T (1024x4096)
    bf16_t* Wkqv = (bf16_t*)(ws + 117440512);        // 512 KiB (256x1024)
    bf16_t* WpT  = (bf16_t*)(ws + 117964800);        // 128 KiB
    bf16_t* kb   = (bf16_t*)(ws + 118095872);        // 1 MiB
    bf16_t* qb   = (bf16_t*)(ws + 119144448);        // 1 MiB
    bf16_t* vT   = (bf16_t*)(ws + 120193024);        // 1 MiB (64 x 8192)
    bf16_t* a0   = (bf16_t*)(ws + 121241600);        // 1 MiB attn out
    float*  r1   = (float*)(ws + 122290176);         // 32 MiB residual1 / x1
    float*  pk0  = (float*)(ws + 155844608);         // 32 MiB FFN2 k-half 0 partial
    float*  pk1  = (float*)(ws);                     // 32 MiB FFN2 k-half 1 (over xb+x1b)

    cast_f32_bf16<<<8192, 256, 0, stream>>>(x, xb, 2097152);
    build_wkqv<<<1024, 256, 0, stream>>>(Wk, Wq, Wv, Wkqv);
    tcast<<<dim3(16, 1), 256, 0, stream>>>(Wp, WpT, 64, 1024);
    tcast<<<dim3(64, 16), 256, 0, stream>>>(W1, W1t, 1024, 4096);
    tcast<<<dim3(16, 64), 256, 0, stream>>>(W2, W2t, 4096, 1024);

    // k,q,v projections (N padded to 256)
    gemm_bt<0><<<64 * 2, 256, 0, stream>>>(xb, Wkqv, 8192, 256, 1024,
                                           nullptr, kb, qb, vT, nullptr, nullptr);
    // causal flash attention: split-KV partials + reduce
    attn_partial<<<1088, 256, 0, stream>>>(qb, kb, vT, po, pml);
    attn_reduce<<<512, 256, 0, stream>>>(po, pml, a0);
    // proj + residual: r1 = x + a0 @ Wp
    gemm_bt<1><<<64 * 8, 256, 0, stream>>>(a0, WpT, 8192, 1024, 64,
                                           r1, nullptr, nullptr, nullptr, x, nullptr);
    // x1 = LN(r1)  (in-place fp32) + bf16 twin
    ln_fused<<<8192, 256, 0, stream>>>(r1, g1, be1, r1, x1b);
    // h = relu(x1 @ W1 + b1)   [256x256 LDS-staged, 512 blocks]
    gemm_ls<2><<<dim3(512, 1), 512, 0, stream>>>(x1b, 1024, W1t, 1024, 4096, 1024,
                                                 hb, b1, nullptr, nullptr);
    // h @ W2 split-K x2 partials  [256x256 LDS-staged, 128 tiles x 2 k-halves]
    gemm_ls<4><<<dim3(128, 2), 512, 0, stream>>>(hb, 4096, W2t, 4096, 1024, 2048,
                                                 nullptr, nullptr, pk0, pk1);
    // out = LN(r1 + pk0 + pk1 + b2)
    ln_sum<<<8192, 256, 0, stream>>>(r1, pk0, pk1, b2, g2, be2, out);
}